// Round 2
// baseline (3252.273 us; speedup 1.0000x reference)
//
#include <hip/hip_runtime.h>
#include <hip/hip_bf16.h>
#include <math.h>

// Inputs may be bf16 or fp32; a device-side flag (derived from pe_w == all-ones:
// first u16 is 0x3F80 iff bf16, 0x0000 iff little-endian fp32 1.0f) selects at
// runtime. The flag is wave-uniform -> cheap branch. Weight sub-tensor offsets
// are passed in ELEMENTS so host code never needs to know the dtype.
__device__ __forceinline__ float ldin(const void* p, size_t i, int isbf) {
  if (isbf) return __bfloat162float(((const __hip_bfloat16*)p)[i]);
  return ((const float*)p)[i];
}

__device__ __forceinline__ float wave_sum(float v) {
#pragma unroll
  for (int o = 32; o > 0; o >>= 1) v += __shfl_down(v, o);
  return v;
}

__device__ __forceinline__ float block_sum(float v, float* sbuf) {
  int lane = threadIdx.x & 63;
  int wid = threadIdx.x >> 6;
#pragma unroll
  for (int o = 32; o > 0; o >>= 1) v += __shfl_down(v, o);
  __syncthreads();
  if (lane == 0) sbuf[wid] = v;
  __syncthreads();
  int nw = blockDim.x >> 6;
  if (wid == 0) {
    float r = (lane < nw) ? sbuf[lane] : 0.f;
#pragma unroll
    for (int o = 4; o > 0; o >>= 1) r += __shfl_down(r, o);
    if (lane == 0) sbuf[0] = r;
  }
  __syncthreads();
  return sbuf[0];
}

__device__ __forceinline__ float block_max(float v, float* sbuf) {
  int lane = threadIdx.x & 63;
  int wid = threadIdx.x >> 6;
#pragma unroll
  for (int o = 32; o > 0; o >>= 1) v = fmaxf(v, __shfl_down(v, o));
  __syncthreads();
  if (lane == 0) sbuf[wid] = v;
  __syncthreads();
  int nw = blockDim.x >> 6;
  if (wid == 0) {
    float r = (lane < nw) ? sbuf[lane] : -INFINITY;
#pragma unroll
    for (int o = 4; o > 0; o >>= 1) r = fmaxf(r, __shfl_down(r, o));
    if (lane == 0) sbuf[0] = r;
  }
  __syncthreads();
  return sbuf[0];
}

__global__ void flag_kernel(const void* pe_w, int* flag) {
  if (threadIdx.x == 0 && blockIdx.x == 0)
    *flag = (((const unsigned short*)pe_w)[0] != 0) ? 1 : 0;
}

// C[M,N] = act(A[M,K] @ W[woff + K*N] + bias[boff + N]) (+= if addto). A,C fp32.
__global__ __launch_bounds__(256) void gemm_bias(const float* __restrict__ A,
                                                 const void* __restrict__ W, size_t woff,
                                                 const void* __restrict__ bias, size_t boff,
                                                 float* __restrict__ C, int M, int N, int K,
                                                 int act, int addto, const int* __restrict__ dflag) {
  const int isbf = *dflag;
  __shared__ float As[32][33];
  __shared__ float Bs[32][33];
  int tx = threadIdx.x & 15;
  int ty = threadIdx.x >> 4;
  int row0 = blockIdx.y * 32;
  int col0 = blockIdx.x * 32;
  float acc00 = 0.f, acc01 = 0.f, acc10 = 0.f, acc11 = 0.f;
  for (int k0 = 0; k0 < K; k0 += 32) {
#pragma unroll
    for (int i = 0; i < 4; ++i) {
      int idx = threadIdx.x + i * 256;
      int r = idx >> 5, c = idx & 31;
      As[r][c] = A[(size_t)(row0 + r) * K + (k0 + c)];
      Bs[r][c] = ldin(W, woff + (size_t)(k0 + r) * N + (col0 + c), isbf);
    }
    __syncthreads();
#pragma unroll
    for (int kk = 0; kk < 32; ++kk) {
      float a0 = As[ty * 2][kk], a1 = As[ty * 2 + 1][kk];
      float b0 = Bs[kk][tx * 2], b1 = Bs[kk][tx * 2 + 1];
      acc00 = fmaf(a0, b0, acc00);
      acc01 = fmaf(a0, b1, acc01);
      acc10 = fmaf(a1, b0, acc10);
      acc11 = fmaf(a1, b1, acc11);
    }
    __syncthreads();
  }
  float accs[2][2] = {{acc00, acc01}, {acc10, acc11}};
#pragma unroll
  for (int i = 0; i < 2; ++i) {
#pragma unroll
    for (int j = 0; j < 2; ++j) {
      int r = row0 + ty * 2 + i;
      int c = col0 + tx * 2 + j;
      float v = accs[i][j] + ldin(bias, boff + c, isbf);
      if (act == 1) v = v * 0.5f * (1.f + erff(v * 0.70710678118654752f));
      size_t o = (size_t)r * N + c;
      if (addto) C[o] += v; else C[o] = v;
    }
  }
}

// LN of (emb + pos): input dtype in, fp32 out. blockDim=256, D=512.
__global__ __launch_bounds__(256) void emb_ln_kernel(const void* __restrict__ emb,
                                                     const void* __restrict__ pos,
                                                     const void* __restrict__ w,
                                                     const void* __restrict__ b,
                                                     float* __restrict__ out, int T, int D,
                                                     const int* __restrict__ dflag) {
  const int isbf = *dflag;
  int row = blockIdx.x;
  int t = row % T;
  __shared__ float sbuf[8];
  int i0 = threadIdx.x, i1 = threadIdx.x + blockDim.x;
  float v0 = ldin(emb, (size_t)row * D + i0, isbf) + ldin(pos, (size_t)t * D + i0, isbf);
  float v1 = ldin(emb, (size_t)row * D + i1, isbf) + ldin(pos, (size_t)t * D + i1, isbf);
  float mean = block_sum(v0 + v1, sbuf) / (float)D;
  float d0 = v0 - mean, d1 = v1 - mean;
  float var = block_sum(d0 * d0 + d1 * d1, sbuf) / (float)D;
  float inv = 1.0f / sqrtf(var + 1e-12f);
  out[(size_t)row * D + i0] = ldin(w, i0, isbf) * d0 * inv + ldin(b, i0, isbf);
  out[(size_t)row * D + i1] = ldin(w, i1, isbf) * d1 * inv + ldin(b, i1, isbf);
}

// LN fp32 in/out (reads complete before writes within the block; rows disjoint).
__global__ __launch_bounds__(256) void ln_kernel(const float* __restrict__ in, float* __restrict__ out,
                                                 const void* __restrict__ w, const void* __restrict__ b,
                                                 size_t wboff, int D, const int* __restrict__ dflag) {
  const int isbf = *dflag;
  int row = blockIdx.x;
  __shared__ float sbuf[8];
  int i0 = threadIdx.x, i1 = threadIdx.x + blockDim.x;
  float v0 = in[(size_t)row * D + i0];
  float v1 = in[(size_t)row * D + i1];
  float mean = block_sum(v0 + v1, sbuf) / (float)D;
  float d0 = v0 - mean, d1 = v1 - mean;
  float var = block_sum(d0 * d0 + d1 * d1, sbuf) / (float)D;
  float inv = 1.0f / sqrtf(var + 1e-12f);
  out[(size_t)row * D + i0] = ldin(w, wboff + i0, isbf) * d0 * inv + ldin(b, wboff + i0, isbf);
  out[(size_t)row * D + i1] = ldin(w, wboff + i1, isbf) * d1 * inv + ldin(b, wboff + i1, isbf);
}

// MHA attention: one block per (b,h,t), 128 threads (T=dk=128). All fp32 ws.
__global__ __launch_bounds__(128) void attn_kernel(const float* __restrict__ q, const float* __restrict__ k,
                                                   const float* __restrict__ v, float* __restrict__ o,
                                                   int B, int H, int T, int dk) {
  int t = blockIdx.x % T;
  int h = (blockIdx.x / T) % H;
  int b = blockIdx.x / (T * H);
  int D = H * dk;
  int tid = threadIdx.x;
  __shared__ float qs[128];
  __shared__ float ps[128];
  __shared__ float sbuf[8];
  qs[tid] = q[(size_t)(b * T + t) * D + h * dk + tid];
  __syncthreads();
  const float* krow = k + (size_t)(b * T + tid) * D + h * dk;
  float sc = 0.f;
#pragma unroll 8
  for (int d = 0; d < 128; ++d) sc = fmaf(qs[d], krow[d], sc);
  sc *= 0.08838834764831845f; // 1/sqrt(128)
  float mx = block_max(sc, sbuf);
  float e = expf(sc - mx);
  float s = block_sum(e, sbuf);
  ps[tid] = e / s;
  __syncthreads();
  float acc = 0.f;
  for (int s2 = 0; s2 < 128; ++s2)
    acc = fmaf(ps[s2], v[(size_t)(b * T + s2) * D + h * dk + tid], acc);
  o[(size_t)(b * T + t) * D + h * dk + tid] = acc;
}

// proj[row,c] = sum_d q[row,d]*CE[c,d]. blockDim=64.
__global__ __launch_bounds__(64) void proj_ce_kernel(const float* __restrict__ q,
                                                     const void* __restrict__ ce,
                                                     float* __restrict__ out, int D, int NC,
                                                     const int* __restrict__ dflag) {
  const int isbf = *dflag;
  int row = blockIdx.x;
  for (int c = 0; c < NC; ++c) {
    float acc = 0.f;
    for (int d = threadIdx.x; d < D; d += 64)
      acc = fmaf(q[(size_t)row * D + d], ldin(ce, (size_t)c * D + d, isbf), acc);
    acc = wave_sum(acc);
    if (threadIdx.x == 0) out[row * NC + c] = acc;
  }
}

__global__ __launch_bounds__(64) void gram_kernel(const void* __restrict__ ce,
                                                  float* __restrict__ G, int D, int NC,
                                                  const int* __restrict__ dflag) {
  const int isbf = *dflag;
  int c = blockIdx.x / NC, c2 = blockIdx.x % NC;
  float acc = 0.f;
  for (int d = threadIdx.x; d < D; d += 64)
    acc = fmaf(ldin(ce, (size_t)c * D + d, isbf), ldin(ce, (size_t)c2 * D + d, isbf), acc);
  acc = wave_sum(acc);
  if (threadIdx.x == 0) G[blockIdx.x] = acc;
}

// sim scores + double softmax + pa. one block per (b,t), 128 threads.
__global__ __launch_bounds__(128) void sim_scores_kernel(
    const float* __restrict__ q, const float* __restrict__ k, const void* __restrict__ qa,
    const void* __restrict__ aq, const float* __restrict__ qc, const float* __restrict__ kc,
    const float* __restrict__ G, float* __restrict__ p_out, float* __restrict__ pa_out,
    int B, int T1, int T2, int D, int NC, const int* __restrict__ dflag) {
  const int isbf = *dflag;
  int t = blockIdx.x % T1;
  int b = blockIdx.x / T1;
  int s = threadIdx.x;  // T2 == 128
  __shared__ float qs[512];
  __shared__ float Gs[25];
  __shared__ float qcs[5];
  __shared__ float sbuf[8];
  for (int i = threadIdx.x; i < D; i += blockDim.x) qs[i] = q[(size_t)(b * T1 + t) * D + i];
  if (threadIdx.x < NC * NC) Gs[threadIdx.x] = G[threadIdx.x];
  if (threadIdx.x < NC) qcs[threadIdx.x] = qc[(b * T1 + t) * NC + threadIdx.x];
  __syncthreads();
  const float* krow = k + (size_t)(b * T2 + s) * D;
  float sc = 0.f;
#pragma unroll 8
  for (int d = 0; d < 512; ++d) sc = fmaf(qs[d], krow[d], sc);
  float qav[5], aqv[5];
#pragma unroll
  for (int c = 0; c < 5; ++c) {
    qav[c] = ldin(qa, (size_t)((b * T1 + t) * T2 + s) * NC + c, isbf);
    aqv[c] = ldin(aq, (size_t)((b * T2 + s) * T1 + t) * NC + c, isbf);
  }
#pragma unroll
  for (int c = 0; c < 5; ++c) {
    sc = fmaf(aqv[c], qcs[c], sc);
    sc = fmaf(qav[c], kc[(b * T2 + s) * NC + c], sc);
#pragma unroll
    for (int c2 = 0; c2 < 5; ++c2) sc = fmaf(qav[c] * Gs[c * 5 + c2], aqv[c2], sc);
  }
  float mx = block_max(sc, sbuf);
  float e = expf(sc - mx);
  float ssum = block_sum(e, sbuf);
  float p = e / ssum;
  float mx2 = block_max(p, sbuf);
  float e2 = expf(1000.f * (p - mx2));
  float s2 = block_sum(e2, sbuf);
  float pf = fminf(fmaxf(e2 / s2, 0.f), 1.f);
  p_out[(size_t)(b * T1 + t) * T2 + s] = pf;
#pragma unroll
  for (int c = 0; c < 5; ++c) {
    float pc = block_sum(pf * aqv[c], sbuf);
    if (threadIdx.x == 0) pa_out[(b * T1 + t) * NC + c] = pc;
  }
}

// x[b,t,d] = sum_s p*k + sum_c pa*CE. one block per (b,t), 512 threads.
__global__ __launch_bounds__(512) void sim_x_kernel(const float* __restrict__ p, const float* __restrict__ k,
                                                    const float* __restrict__ pa,
                                                    const void* __restrict__ ce,
                                                    float* __restrict__ x, int B, int T1, int T2, int D, int NC,
                                                    const int* __restrict__ dflag) {
  const int isbf = *dflag;
  int t = blockIdx.x % T1;
  int b = blockIdx.x / T1;
  int d = threadIdx.x;
  __shared__ float ps[128];
  __shared__ float pav[5];
  if (threadIdx.x < T2) ps[threadIdx.x] = p[(size_t)(b * T1 + t) * T2 + threadIdx.x];
  if (threadIdx.x < NC) pav[threadIdx.x] = pa[(b * T1 + t) * NC + threadIdx.x];
  __syncthreads();
  float acc = 0.f;
  for (int s = 0; s < 128; ++s) acc = fmaf(ps[s], k[(size_t)(b * T2 + s) * D + d], acc);
#pragma unroll
  for (int c = 0; c < 5; ++c) acc = fmaf(pav[c], ldin(ce, (size_t)c * D + d, isbf), acc);
  x[(size_t)(b * T1 + t) * D + d] = acc;
}

__global__ __launch_bounds__(512) void mean_kernel(const float* __restrict__ x, float* __restrict__ xm,
                                                   int T, int D) {
  int b = blockIdx.x;
  int d = threadIdx.x;
  float acc = 0.f;
  for (int t = 0; t < T; ++t) acc += x[(size_t)(b * T + t) * D + d];
  xm[(size_t)b * D + d] = acc / (float)T;
}

__global__ __launch_bounds__(64) void cls_kernel(const float* __restrict__ xm,
                                                 const void* __restrict__ w,
                                                 const void* __restrict__ bias,
                                                 void* __restrict__ out, int D, int NO,
                                                 const int* __restrict__ dflag) {
  const int isbf = *dflag;
  int j = blockIdx.x % NO;
  int b = blockIdx.x / NO;
  float acc = 0.f;
  for (int d = threadIdx.x; d < D; d += 64)
    acc = fmaf(xm[(size_t)b * D + d], ldin(w, (size_t)d * NO + j, isbf), acc);
  acc = wave_sum(acc);
  if (threadIdx.x == 0) {
    float val = acc + ldin(bias, j, isbf);
    if (isbf) ((__hip_bfloat16*)out)[b * NO + j] = __float2bfloat16(val);
    else ((float*)out)[b * NO + j] = val;
  }
}

extern "C" void kernel_launch(void* const* d_in, const int* in_sizes, int n_in,
                              void* d_out, int out_size, void* d_ws, size_t ws_size,
                              hipStream_t stream) {
  const int B = 4, T = 128, D = 512, H = 4, NL = 4, DFF = 2048, NC = 5;
  const void *q_emb = d_in[0], *a_emb = d_in[1], *qa = d_in[2], *aqr = d_in[3],
             *ce = d_in[4], *pos = d_in[5], *pe_w = d_in[6], *pe_b = d_in[7],
             *Wq = d_in[8], *bq = d_in[9], *Wk = d_in[10], *bk = d_in[11],
             *Wv = d_in[12], *bv = d_in[13], *Wo = d_in[14], *bo = d_in[15],
             *ff1w = d_in[16], *ff1b = d_in[17], *ff2w = d_in[18], *ff2b = d_in[19],
             *lnin_w = d_in[20], *lnin_b = d_in[21], *lnout_w = d_in[22], *lnout_b = d_in[23],
             *simWq = d_in[24], *simbq = d_in[25], *simWk = d_in[26], *simbk = d_in[27],
             *clsw = d_in[28], *clsb = d_in[29];
  float* ws = (float*)d_ws;

  // Compact aliased layout: 7S + 16 floats ~= 7.0 MB.
  const size_t S = (size_t)B * T * D;  // 262144
  float* qe = ws;
  float* ae = ws + S;
  float* hb = ws + 2 * S;
  float* rb = ws + 3 * S;   // 4S region: qb/kb/vb/ob during attn; ffb during FFN
  float* qb = rb;
  float* kb = rb + S;
  float* vb = rb + 2 * S;
  float* ob = rb + 3 * S;
  float* ffb = rb;          // aliases qb..ob (dead when FFN runs)
  float* pbuf = rb + 2 * S; // sim phase: vb/ob slots are free
  float* pabuf = pbuf + (size_t)B * T * T;
  float* qcbuf = pabuf + B * T * NC;
  float* kcbuf = qcbuf + B * T * NC;
  float* Gbuf = kcbuf + B * T * NC;
  float* xmean = Gbuf + 32;
  float* xsim = rb + 3 * S;
  int* dflag = (int*)(ws + 7 * S);

  const int M = B * T;  // 512
  dim3 gD(D / 32, M / 32);
  dim3 gF(DFF / 32, M / 32);

  flag_kernel<<<1, 64, 0, stream>>>(pe_w, dflag);

  for (int e = 0; e < 2; ++e) {
    float* x = (e == 0) ? qe : ae;
    const void* emb = (e == 0) ? q_emb : a_emb;
    emb_ln_kernel<<<M, 256, 0, stream>>>(emb, pos, pe_w, pe_b, x, T, D, dflag);
    for (int l = 0; l < NL; ++l) {
      size_t wDD = (size_t)l * D * D, bD = (size_t)l * D;
      gemm_bias<<<gD, 256, 0, stream>>>(x, Wq, wDD, bq, bD, qb, M, D, D, 0, 0, dflag);
      gemm_bias<<<gD, 256, 0, stream>>>(x, Wk, wDD, bk, bD, kb, M, D, D, 0, 0, dflag);
      gemm_bias<<<gD, 256, 0, stream>>>(x, Wv, wDD, bv, bD, vb, M, D, D, 0, 0, dflag);
      attn_kernel<<<B * H * T, 128, 0, stream>>>(qb, kb, vb, ob, B, H, T, D / H);
      gemm_bias<<<gD, 256, 0, stream>>>(ob, Wo, wDD, bo, bD, x, M, D, D, 0, 1, dflag);
      ln_kernel<<<M, 256, 0, stream>>>(x, hb, lnin_w, lnin_b, bD, D, dflag);
      gemm_bias<<<gF, 256, 0, stream>>>(hb, ff1w, (size_t)l * D * DFF, ff1b, (size_t)l * DFF,
                                        ffb, M, DFF, D, 1, 0, dflag);
      gemm_bias<<<gD, 256, 0, stream>>>(ffb, ff2w, (size_t)l * DFF * D, ff2b, bD,
                                        x, M, D, DFF, 0, 1, dflag);
      ln_kernel<<<M, 256, 0, stream>>>(x, x, lnout_w, lnout_b, bD, D, dflag);
    }
  }

  // SimAttn head
  gemm_bias<<<gD, 256, 0, stream>>>(qe, simWq, 0, simbq, 0, qb, M, D, D, 0, 0, dflag);
  gemm_bias<<<gD, 256, 0, stream>>>(ae, simWk, 0, simbk, 0, kb, M, D, D, 0, 0, dflag);
  proj_ce_kernel<<<M, 64, 0, stream>>>(qb, ce, qcbuf, D, NC, dflag);
  proj_ce_kernel<<<M, 64, 0, stream>>>(kb, ce, kcbuf, D, NC, dflag);
  gram_kernel<<<NC * NC, 64, 0, stream>>>(ce, Gbuf, D, NC, dflag);
  sim_scores_kernel<<<B * T, 128, 0, stream>>>(qb, kb, qa, aqr, qcbuf, kcbuf, Gbuf, pbuf, pabuf,
                                               B, T, T, D, NC, dflag);
  sim_x_kernel<<<B * T, 512, 0, stream>>>(pbuf, kb, pabuf, ce, xsim, B, T, T, D, NC, dflag);
  mean_kernel<<<B, 512, 0, stream>>>(xsim, xmean, T, D);
  cls_kernel<<<B * 3, 64, 0, stream>>>(xmean, clsw, clsb, d_out, D, 3, dflag);
}

// Round 6
// 2420.670 us; speedup vs baseline: 1.3435x; 1.3435x over previous
//
#include <hip/hip_runtime.h>
#include <hip/hip_bf16.h>
#include <math.h>

typedef unsigned short u16;
typedef __attribute__((ext_vector_type(8))) short bf16x8;   // 8 bf16 (4 VGPRs)
typedef __attribute__((ext_vector_type(4))) float f32x4;

// Inputs may be bf16 or fp32; device-side flag (pe_w is all-ones: first u16 is
// 0x3F80 iff bf16, 0x0000 iff little-endian fp32 1.0f) selects at runtime.
// Evidence so far (r1-r5): every hard-coded-bf16 read NaN'd, flag version passed
// => inputs are fp32; but keep the flag so both dtypes stay correct.
__device__ __forceinline__ float ldin(const void* p, size_t i, int isbf) {
  if (isbf) return __bfloat162float(((const __hip_bfloat16*)p)[i]);
  return ((const float*)p)[i];
}
__device__ __forceinline__ float bfu(u16 u) { return __builtin_bit_cast(float, (unsigned)u << 16); }
__device__ __forceinline__ u16 f2bf(float x) {  // round-to-nearest-even
  unsigned u = __builtin_bit_cast(unsigned, x);
  unsigned r = u + 0x7FFFu + ((u >> 16) & 1u);
  return (u16)(r >> 16);
}

__device__ __forceinline__ float wave_sum(float v) {
#pragma unroll
  for (int o = 32; o > 0; o >>= 1) v += __shfl_down(v, o);
  return v;
}

__device__ __forceinline__ float block_sum(float v, float* sbuf) {
  int lane = threadIdx.x & 63;
  int wid = threadIdx.x >> 6;
#pragma unroll
  for (int o = 32; o > 0; o >>= 1) v += __shfl_down(v, o);
  __syncthreads();
  if (lane == 0) sbuf[wid] = v;
  __syncthreads();
  int nw = blockDim.x >> 6;
  if (wid == 0) {
    float r = (lane < nw) ? sbuf[lane] : 0.f;
#pragma unroll
    for (int o = 4; o > 0; o >>= 1) r += __shfl_down(r, o);
    if (lane == 0) sbuf[0] = r;
  }
  __syncthreads();
  return sbuf[0];
}

__device__ __forceinline__ float block_max(float v, float* sbuf) {
  int lane = threadIdx.x & 63;
  int wid = threadIdx.x >> 6;
#pragma unroll
  for (int o = 32; o > 0; o >>= 1) v = fmaxf(v, __shfl_down(v, o));
  __syncthreads();
  if (lane == 0) sbuf[wid] = v;
  __syncthreads();
  int nw = blockDim.x >> 6;
  if (wid == 0) {
    float r = (lane < nw) ? sbuf[lane] : -INFINITY;
#pragma unroll
    for (int o = 4; o > 0; o >>= 1) r = fmaxf(r, __shfl_down(r, o));
    if (lane == 0) sbuf[0] = r;
  }
  __syncthreads();
  return sbuf[0];
}

__global__ void flag_kernel(const void* pe_w, int* flag) {
  if (threadIdx.x == 0 && blockIdx.x == 0)
    *flag = (((const unsigned short*)pe_w)[0] != 0) ? 1 : 0;
}

// ---------------------------------------------------------------------------
// MFMA GEMM, dtype-safe: C[M,N] = act(A[M,K](fp32) @ W[woff..]([K,N], flag dtype)
//                                     + bias[boff..]) (+= if addto)
// 64x64 tile, BK=32, 256 threads = 4 waves, each a 32x32 quadrant.
// BOTH A and W split hi+lo bf16; 3 MFMAs (ah*wh, al*wh, ah*wl) per fragment
// => ~2^-16 relative accuracy with fp32 accumulate (al*wl dropped).
// ---------------------------------------------------------------------------
__global__ __launch_bounds__(256) void gemm_mfma(
    const float* __restrict__ A, const void* __restrict__ W, size_t woff,
    const void* __restrict__ bias, size_t boff,
    float* __restrict__ C, int M, int N, int K, int act, int addto,
    const int* __restrict__ dflag) {
  const int isbf = *dflag;
  __shared__ __align__(16) u16 Ah[64][40];  // +8 pad: 80B row stride, 2-way bank alias only
  __shared__ __align__(16) u16 Al[64][40];
  __shared__ __align__(16) u16 Wh[64][40];  // n-major (transposed)
  __shared__ __align__(16) u16 Wl[64][40];

  int tid = threadIdx.x;
  int row0 = blockIdx.y * 64, col0 = blockIdx.x * 64;

  int wid = tid >> 6, lane = tid & 63;
  int quad = lane >> 4, lm = lane & 15;
  int mrow = (wid & 1) * 32, ncol = (wid >> 1) * 32;

  f32x4 acc[2][2] = {};

  int ar = tid >> 2, akc = (tid & 3) * 8;   // A staging: 8 fp32/thread (64 rows x 32 k)
  int bk = tid >> 3, bn0 = (tid & 7) * 8;   // W staging: 8 elems/thread (32 k x 64 n)

  for (int k0 = 0; k0 < K; k0 += 32) {
    // --- stage A: fp32 -> hi+lo bf16 ---
    const float* ap = A + (size_t)(row0 + ar) * K + k0 + akc;
    float av[8];
    *(float4*)(av) = *(const float4*)ap;
    *(float4*)(av + 4) = *(const float4*)(ap + 4);
    unsigned hp[4], lp[4];
#pragma unroll
    for (int j = 0; j < 4; ++j) {
      u16 h0 = f2bf(av[2 * j]);
      u16 h1 = f2bf(av[2 * j + 1]);
      u16 l0 = f2bf(av[2 * j] - bfu(h0));
      u16 l1 = f2bf(av[2 * j + 1] - bfu(h1));
      hp[j] = (unsigned)h0 | ((unsigned)h1 << 16);
      lp[j] = (unsigned)l0 | ((unsigned)l1 << 16);
    }
    *(uint4*)&Ah[ar][akc] = make_uint4(hp[0], hp[1], hp[2], hp[3]);
    *(uint4*)&Al[ar][akc] = make_uint4(lp[0], lp[1], lp[2], lp[3]);
    // --- stage W (dtype branch, wave-uniform) -> hi+lo bf16, transposed to n-major ---
    float wv[8];
    size_t welem = woff + (size_t)(k0 + bk) * N + col0 + bn0;
    if (isbf) {
      const u16* wp = (const u16*)W + welem;
      uint4 raw = *(const uint4*)wp;
      wv[0] = bfu((u16)(raw.x & 0xFFFF)); wv[1] = bfu((u16)(raw.x >> 16));
      wv[2] = bfu((u16)(raw.y & 0xFFFF)); wv[3] = bfu((u16)(raw.y >> 16));
      wv[4] = bfu((u16)(raw.z & 0xFFFF)); wv[5] = bfu((u16)(raw.z >> 16));
      wv[6] = bfu((u16)(raw.w & 0xFFFF)); wv[7] = bfu((u16)(raw.w >> 16));
    } else {
      const float* wp = (const float*)W + welem;
      *(float4*)(wv) = *(const float4*)wp;
      *(float4*)(wv + 4) = *(const float4*)(wp + 4);
    }
#pragma unroll
    for (int i = 0; i < 8; ++i) {
      u16 h = f2bf(wv[i]);
      u16 l = f2bf(wv[i] - bfu(h));   // == 0 when W is bf16
      Wh[bn0 + i][bk] = h;
      Wl[bn0 + i][bk] = l;
    }
    __syncthreads();
    // --- compute: 12 MFMAs/wave (2 m x 2 n x {ah*wh, al*wh, ah*wl}) ---
#pragma unroll
    for (int mi = 0; mi < 2; ++mi) {
      bf16x8 ah = *(const bf16x8*)&Ah[mrow + mi * 16 + lm][quad * 8];
      bf16x8 al = *(const bf16x8*)&Al[mrow + mi * 16 + lm][quad * 8];
#pragma unroll
      for (int ni = 0; ni < 2; ++ni) {
        bf16x8 wh = *(const bf16x8*)&Wh[ncol + ni * 16 + lm][quad * 8];
        bf16x8 wl = *(const bf16x8*)&Wl[ncol + ni * 16 + lm][quad * 8];
        acc[mi][ni] = __builtin_amdgcn_mfma_f32_16x16x32_bf16(ah, wh, acc[mi][ni], 0, 0, 0);
        acc[mi][ni] = __builtin_amdgcn_mfma_f32_16x16x32_bf16(al, wh, acc[mi][ni], 0, 0, 0);
        acc[mi][ni] = __builtin_amdgcn_mfma_f32_16x16x32_bf16(ah, wl, acc[mi][ni], 0, 0, 0);
      }
    }
    __syncthreads();
  }
  // C/D layout: col=lane&15, row=quad*4+reg (m89-verified)
#pragma unroll
  for (int mi = 0; mi < 2; ++mi) {
#pragma unroll
    for (int ni = 0; ni < 2; ++ni) {
      int colg = col0 + ncol + ni * 16 + lm;
      float bv = ldin(bias, boff + colg, isbf);
#pragma unroll
      for (int r = 0; r < 4; ++r) {
        int rowg = row0 + mrow + mi * 16 + quad * 4 + r;
        float v = acc[mi][ni][r] + bv;
        if (act) v = v * 0.5f * (1.f + erff(v * 0.70710678118654752f));
        size_t o = (size_t)rowg * N + colg;
        if (addto) C[o] += v; else C[o] = v;
      }
    }
  }
}

// ---- everything below is VERBATIM the round-2 passing code ----

__global__ __launch_bounds__(256) void emb_ln_kernel(const void* __restrict__ emb,
                                                     const void* __restrict__ pos,
                                                     const void* __restrict__ w,
                                                     const void* __restrict__ b,
                                                     float* __restrict__ out, int T, int D,
                                                     const int* __restrict__ dflag) {
  const int isbf = *dflag;
  int row = blockIdx.x;
  int t = row % T;
  __shared__ float sbuf[8];
  int i0 = threadIdx.x, i1 = threadIdx.x + 256;
  float v0 = ldin(emb, (size_t)row * D + i0, isbf) + ldin(pos, (size_t)t * D + i0, isbf);
  float v1 = ldin(emb, (size_t)row * D + i1, isbf) + ldin(pos, (size_t)t * D + i1, isbf);
  float mean = block_sum(v0 + v1, sbuf) / (float)D;
  float d0 = v0 - mean, d1 = v1 - mean;
  float var = block_sum(d0 * d0 + d1 * d1, sbuf) / (float)D;
  float inv = 1.0f / sqrtf(var + 1e-12f);
  out[(size_t)row * D + i0] = ldin(w, i0, isbf) * d0 * inv + ldin(b, i0, isbf);
  out[(size_t)row * D + i1] = ldin(w, i1, isbf) * d1 * inv + ldin(b, i1, isbf);
}

__global__ __launch_bounds__(256) void ln_kernel(const float* __restrict__ in, float* __restrict__ out,
                                                 const void* __restrict__ w, const void* __restrict__ b,
                                                 size_t wboff, int D, const int* __restrict__ dflag) {
  const int isbf = *dflag;
  int row = blockIdx.x;
  __shared__ float sbuf[8];
  int i0 = threadIdx.x, i1 = threadIdx.x + 256;
  float v0 = in[(size_t)row * D + i0];
  float v1 = in[(size_t)row * D + i1];
  float mean = block_sum(v0 + v1, sbuf) / (float)D;
  float d0 = v0 - mean, d1 = v1 - mean;
  float var = block_sum(d0 * d0 + d1 * d1, sbuf) / (float)D;
  float inv = 1.0f / sqrtf(var + 1e-12f);
  out[(size_t)row * D + i0] = ldin(w, wboff + i0, isbf) * d0 * inv + ldin(b, wboff + i0, isbf);
  out[(size_t)row * D + i1] = ldin(w, wboff + i1, isbf) * d1 * inv + ldin(b, wboff + i1, isbf);
}

__global__ __launch_bounds__(128) void attn_kernel(const float* __restrict__ q, const float* __restrict__ k,
                                                   const float* __restrict__ v, float* __restrict__ o,
                                                   int B, int H, int T, int dk) {
  int t = blockIdx.x % T;
  int h = (blockIdx.x / T) % H;
  int b = blockIdx.x / (T * H);
  int D = H * dk;
  int tid = threadIdx.x;
  __shared__ float qs[128];
  __shared__ float ps[128];
  __shared__ float sbuf[8];
  qs[tid] = q[(size_t)(b * T + t) * D + h * dk + tid];
  __syncthreads();
  const float* krow = k + (size_t)(b * T + tid) * D + h * dk;
  float sc = 0.f;
#pragma unroll 8
  for (int d = 0; d < 128; ++d) sc = fmaf(qs[d], krow[d], sc);
  sc *= 0.08838834764831845f;
  float mx = block_max(sc, sbuf);
  float e = expf(sc - mx);
  float s = block_sum(e, sbuf);
  ps[tid] = e / s;
  __syncthreads();
  float acc = 0.f;
  for (int s2 = 0; s2 < 128; ++s2)
    acc = fmaf(ps[s2], v[(size_t)(b * T + s2) * D + h * dk + tid], acc);
  o[(size_t)(b * T + t) * D + h * dk + tid] = acc;
}

__global__ __launch_bounds__(64) void proj_ce_kernel(const float* __restrict__ q,
                                                     const void* __restrict__ ce,
                                                     float* __restrict__ out, int D, int NC,
                                                     const int* __restrict__ dflag) {
  const int isbf = *dflag;
  int row = blockIdx.x;
  for (int c = 0; c < NC; ++c) {
    float acc = 0.f;
    for (int d = threadIdx.x; d < D; d += 64)
      acc = fmaf(q[(size_t)row * D + d], ldin(ce, (size_t)c * D + d, isbf), acc);
    acc = wave_sum(acc);
    if (threadIdx.x == 0) out[row * NC + c] = acc;
  }
}

__global__ __launch_bounds__(64) void gram_kernel(const void* __restrict__ ce,
                                                  float* __restrict__ G, int D, int NC,
                                                  const int* __restrict__ dflag) {
  const int isbf = *dflag;
  int c = blockIdx.x / NC, c2 = blockIdx.x % NC;
  float acc = 0.f;
  for (int d = threadIdx.x; d < D; d += 64)
    acc = fmaf(ldin(ce, (size_t)c * D + d, isbf), ldin(ce, (size_t)c2 * D + d, isbf), acc);
  acc = wave_sum(acc);
  if (threadIdx.x == 0) G[blockIdx.x] = acc;
}

__global__ __launch_bounds__(128) void sim_scores_kernel(
    const float* __restrict__ q, const float* __restrict__ k, const void* __restrict__ qa,
    const void* __restrict__ aq, const float* __restrict__ qc, const float* __restrict__ kc,
    const float* __restrict__ G, float* __restrict__ p_out, float* __restrict__ pa_out,
    int B, int T1, int T2, int D, int NC, const int* __restrict__ dflag) {
  const int isbf = *dflag;
  int t = blockIdx.x % T1;
  int b = blockIdx.x / T1;
  int s = threadIdx.x;
  __shared__ float qs[512];
  __shared__ float Gs[25];
  __shared__ float qcs[5];
  __shared__ float sbuf[8];
  for (int i = threadIdx.x; i < D; i += 128) qs[i] = q[(size_t)(b * T1 + t) * D + i];
  if (threadIdx.x < NC * NC) Gs[threadIdx.x] = G[threadIdx.x];
  if (threadIdx.x < NC) qcs[threadIdx.x] = qc[(b * T1 + t) * NC + threadIdx.x];
  __syncthreads();
  const float* krow = k + (size_t)(b * T2 + s) * D;
  float sc = 0.f;
#pragma unroll 8
  for (int d = 0; d < 512; ++d) sc = fmaf(qs[d], krow[d], sc);
  float qav[5], aqv[5];
#pragma unroll
  for (int c = 0; c < 5; ++c) {
    qav[c] = ldin(qa, (size_t)((b * T1 + t) * T2 + s) * NC + c, isbf);
    aqv[c] = ldin(aq, (size_t)((b * T2 + s) * T1 + t) * NC + c, isbf);
  }
#pragma unroll
  for (int c = 0; c < 5; ++c) {
    sc = fmaf(aqv[c], qcs[c], sc);
    sc = fmaf(qav[c], kc[(b * T2 + s) * NC + c], sc);
#pragma unroll
    for (int c2 = 0; c2 < 5; ++c2) sc = fmaf(qav[c] * Gs[c * 5 + c2], aqv[c2], sc);
  }
  float mx = block_max(sc, sbuf);
  float e = expf(sc - mx);
  float ssum = block_sum(e, sbuf);
  float p = e / ssum;
  float mx2 = block_max(p, sbuf);
  float e2 = expf(1000.f * (p - mx2));
  float s2 = block_sum(e2, sbuf);
  float pf = fminf(fmaxf(e2 / s2, 0.f), 1.f);
  p_out[(size_t)(b * T1 + t) * T2 + s] = pf;
#pragma unroll
  for (int c = 0; c < 5; ++c) {
    float pc = block_sum(pf * aqv[c], sbuf);
    if (threadIdx.x == 0) pa_out[(b * T1 + t) * NC + c] = pc;
  }
}

__global__ __launch_bounds__(512) void sim_x_kernel(const float* __restrict__ p, const float* __restrict__ k,
                                                    const float* __restrict__ pa,
                                                    const void* __restrict__ ce,
                                                    float* __restrict__ x, int B, int T1, int T2, int D, int NC,
                                                    const int* __restrict__ dflag) {
  const int isbf = *dflag;
  int t = blockIdx.x % T1;
  int b = blockIdx.x / T1;
  int d = threadIdx.x;
  __shared__ float ps[128];
  __shared__ float pav[5];
  if (threadIdx.x < T2) ps[threadIdx.x] = p[(size_t)(b * T1 + t) * T2 + threadIdx.x];
  if (threadIdx.x < NC) pav[threadIdx.x] = pa[(b * T1 + t) * NC + threadIdx.x];
  __syncthreads();
  float acc = 0.f;
  for (int s = 0; s < 128; ++s) acc = fmaf(ps[s], k[(size_t)(b * T2 + s) * D + d], acc);
#pragma unroll
  for (int c = 0; c < 5; ++c) acc = fmaf(pav[c], ldin(ce, (size_t)c * D + d, isbf), acc);
  x[(size_t)(b * T1 + t) * D + d] = acc;
}

__global__ __launch_bounds__(512) void mean_kernel(const float* __restrict__ x, float* __restrict__ xm,
                                                   int T, int D) {
  int b = blockIdx.x;
  int d = threadIdx.x;
  float acc = 0.f;
  for (int t = 0; t < T; ++t) acc += x[(size_t)(b * T + t) * D + d];
  xm[(size_t)b * D + d] = acc / (float)T;
}

__global__ __launch_bounds__(64) void cls_kernel(const float* __restrict__ xm,
                                                 const void* __restrict__ w,
                                                 const void* __restrict__ bias,
                                                 void* __restrict__ out, int D, int NO,
                                                 const int* __restrict__ dflag) {
  const int isbf = *dflag;
  int j = blockIdx.x % NO;
  int b = blockIdx.x / NO;
  float acc = 0.f;
  for (int d = threadIdx.x; d < D; d += 64)
    acc = fmaf(xm[(size_t)b * D + d], ldin(w, (size_t)d * NO + j, isbf), acc);
  acc = wave_sum(acc);
  if (threadIdx.x == 0) {
    float val = acc + ldin(bias, j, isbf);
    if (isbf) ((__hip_bfloat16*)out)[b * NO + j] = __float2bfloat16(val);
    else ((float*)out)[b * NO + j] = val;
  }
}

extern "C" void kernel_launch(void* const* d_in, const int* in_sizes, int n_in,
                              void* d_out, int out_size, void* d_ws, size_t ws_size,
                              hipStream_t stream) {
  const int B = 4, T = 128, D = 512, H = 4, NL = 4, DFF = 2048, NC = 5;
  const void *q_emb = d_in[0], *a_emb = d_in[1], *qa = d_in[2], *aqr = d_in[3],
             *ce = d_in[4], *pos = d_in[5], *pe_w = d_in[6], *pe_b = d_in[7],
             *Wq = d_in[8], *bq = d_in[9], *Wk = d_in[10], *bk = d_in[11],
             *Wv = d_in[12], *bv = d_in[13], *Wo = d_in[14], *bo = d_in[15],
             *ff1w = d_in[16], *ff1b = d_in[17], *ff2w = d_in[18], *ff2b = d_in[19],
             *lnin_w = d_in[20], *lnin_b = d_in[21], *lnout_w = d_in[22], *lnout_b = d_in[23],
             *simWq = d_in[24], *simbq = d_in[25], *simWk = d_in[26], *simbk = d_in[27],
             *clsw = d_in[28], *clsb = d_in[29];
  float* ws = (float*)d_ws;

  // ws layout: VERBATIM round 2 (proven): 7S + flag.
  const size_t S = (size_t)512 * 512;
  float* qe = ws;
  float* ae = ws + S;
  float* hb = ws + 2 * S;
  float* rb = ws + 3 * S;
  float* qb = rb;
  float* kb = rb + S;
  float* vb = rb + 2 * S;
  float* ob = rb + 3 * S;
  float* ffb = rb;
  float* pbuf = rb + 2 * S;
  float* pabuf = pbuf + 65536;
  float* qcbuf = pabuf + 2560;
  float* kcbuf = qcbuf + 2560;
  float* Gbuf = kcbuf + 2560;
  float* xmean = Gbuf + 32;
  float* xsim = rb + 3 * S;
  int* dflag = (int*)(ws + 7 * S);

  const int M = B * T;  // 512
  dim3 gD(8, 8);    // N=512,  M=512, 64x64 tiles
  dim3 gF1(32, 8);  // N=2048, M=512
  dim3 gF2(8, 8);   // N=512,  M=512, K=2048

  flag_kernel<<<1, 64, 0, stream>>>(pe_w, dflag);

  for (int e = 0; e < 2; ++e) {
    float* x = (e == 0) ? qe : ae;
    const void* emb = (e == 0) ? q_emb : a_emb;
    emb_ln_kernel<<<M, 256, 0, stream>>>(emb, pos, pe_w, pe_b, x, T, D, dflag);
    for (int l = 0; l < NL; ++l) {
      size_t wDD = (size_t)l * D * D, bD = (size_t)l * D;
      gemm_mfma<<<gD, 256, 0, stream>>>(x, Wq, wDD, bq, bD, qb, M, D, D, 0, 0, dflag);
      gemm_mfma<<<gD, 256, 0, stream>>>(x, Wk, wDD, bk, bD, kb, M, D, D, 0, 0, dflag);
      gemm_mfma<<<gD, 256, 0, stream>>>(x, Wv, wDD, bv, bD, vb, M, D, D, 0, 0, dflag);
      attn_kernel<<<B * H * T, 128, 0, stream>>>(qb, kb, vb, ob, B, H, T, D / H);
      gemm_mfma<<<gD, 256, 0, stream>>>(ob, Wo, wDD, bo, bD, x, M, D, D, 0, 1, dflag);
      ln_kernel<<<M, 256, 0, stream>>>(x, hb, lnin_w, lnin_b, bD, D, dflag);
      gemm_mfma<<<gF1, 256, 0, stream>>>(hb, ff1w, (size_t)l * D * DFF, ff1b, (size_t)l * DFF,
                                         ffb, M, DFF, D, 1, 0, dflag);
      gemm_mfma<<<gF2, 256, 0, stream>>>(ffb, ff2w, (size_t)l * DFF * D, ff2b, bD,
                                         x, M, D, DFF, 0, 1, dflag);
      ln_kernel<<<M, 256, 0, stream>>>(x, x, lnout_w, lnout_b, bD, D, dflag);
    }
  }

  gemm_mfma<<<gD, 256, 0, stream>>>(qe, simWq, 0, simbq, 0, qb, M, D, D, 0, 0, dflag);
  gemm_mfma<<<gD, 256, 0, stream>>>(ae, simWk, 0, simbk, 0, kb, M, D, D, 0, 0, dflag);
  proj_ce_kernel<<<M, 64, 0, stream>>>(qb, ce, qcbuf, D, NC, dflag);
  proj_ce_kernel<<<M, 64, 0, stream>>>(kb, ce, kcbuf, D, NC, dflag);
  gram_kernel<<<NC * NC, 64, 0, stream>>>(ce, Gbuf, D, NC, dflag);
  sim_scores_kernel<<<B * T, 128, 0, stream>>>(qb, kb, qa, aqr, qcbuf, kcbuf, Gbuf, pbuf, pabuf,
                                               B, T, T, D, NC, dflag);
  sim_x_kernel<<<B * T, 512, 0, stream>>>(pbuf, kb, pabuf, ce, xsim, B, T, T, D, NC, dflag);
  mean_kernel<<<B, 512, 0, stream>>>(xsim, xmean, T, D);
  cls_kernel<<<B * 3, 64, 0, stream>>>(xmean, clsw, clsb, d_out, D, 3, dflag);
}

// Round 7
// 899.294 us; speedup vs baseline: 3.6165x; 2.6917x over previous
//
#include <hip/hip_runtime.h>
#include <hip/hip_bf16.h>
#include <math.h>

typedef unsigned short u16;
typedef __attribute__((ext_vector_type(8))) short bf16x8;   // 8 bf16 (4 VGPRs)
typedef __attribute__((ext_vector_type(4))) float f32x4;

// Inputs may be bf16 or fp32; device flag (pe_w all-ones: first u16 0x3F80 iff
// bf16, 0x0000 iff fp32 1.0f). r1-r6 evidence: inputs are fp32, but keep flag.
__device__ __forceinline__ float ldin(const void* p, size_t i, int isbf) {
  if (isbf) return __bfloat162float(((const __hip_bfloat16*)p)[i]);
  return ((const float*)p)[i];
}
__device__ __forceinline__ float bfu(u16 u) { return __builtin_bit_cast(float, (unsigned)u << 16); }
__device__ __forceinline__ u16 f2bf(float x) {  // round-to-nearest-even
  unsigned u = __builtin_bit_cast(unsigned, x);
  unsigned r = u + 0x7FFFu + ((u >> 16) & 1u);
  return (u16)(r >> 16);
}

__device__ __forceinline__ float wave_sum(float v) {
#pragma unroll
  for (int o = 32; o > 0; o >>= 1) v += __shfl_down(v, o);
  return v;
}

__device__ __forceinline__ float block_sum(float v, float* sbuf) {
  int lane = threadIdx.x & 63;
  int wid = threadIdx.x >> 6;
#pragma unroll
  for (int o = 32; o > 0; o >>= 1) v += __shfl_down(v, o);
  __syncthreads();
  if (lane == 0) sbuf[wid] = v;
  __syncthreads();
  int nw = blockDim.x >> 6;
  if (wid == 0) {
    float r = (lane < nw) ? sbuf[lane] : 0.f;
#pragma unroll
    for (int o = 4; o > 0; o >>= 1) r += __shfl_down(r, o);
    if (lane == 0) sbuf[0] = r;
  }
  __syncthreads();
  return sbuf[0];
}

__device__ __forceinline__ float block_max(float v, float* sbuf) {
  int lane = threadIdx.x & 63;
  int wid = threadIdx.x >> 6;
#pragma unroll
  for (int o = 32; o > 0; o >>= 1) v = fmaxf(v, __shfl_down(v, o));
  __syncthreads();
  if (lane == 0) sbuf[wid] = v;
  __syncthreads();
  int nw = blockDim.x >> 6;
  if (wid == 0) {
    float r = (lane < nw) ? sbuf[lane] : -INFINITY;
#pragma unroll
    for (int o = 4; o > 0; o >>= 1) r = fmaxf(r, __shfl_down(r, o));
    if (lane == 0) sbuf[0] = r;
  }
  __syncthreads();
  return sbuf[0];
}

__global__ void flag_kernel(const void* pe_w, int* flag) {
  if (threadIdx.x == 0 && blockIdx.x == 0)
    *flag = (((const unsigned short*)pe_w)[0] != 0) ? 1 : 0;
}

// ===========================================================================
// FAST PATH kernels
// ===========================================================================

// Weight convert+transpose: src [K][N] (flag dtype, up to 3 z-segments) ->
// dst hi/lo u16 planes [nseg*N][K]. 32x32 LDS tile, 256 threads (32x8).
__global__ __launch_bounds__(256) void convT(
    const void* __restrict__ S0, const void* __restrict__ S1, const void* __restrict__ S2,
    size_t woff, int K, int N, u16* __restrict__ Dh, u16* __restrict__ Dl,
    const int* __restrict__ dflag) {
  const int isbf = *dflag;
  const void* S = (blockIdx.z == 0) ? S0 : ((blockIdx.z == 1) ? S1 : S2);
  int n0 = blockIdx.x * 32, k0 = blockIdx.y * 32;
  __shared__ float t[32][33];
  int tx = threadIdx.x & 31, ty = threadIdx.x >> 5;
#pragma unroll
  for (int j = 0; j < 4; ++j) {
    int r = ty + j * 8;  // local k
    t[r][tx] = ldin(S, woff + (size_t)(k0 + r) * N + n0 + tx, isbf);
  }
  __syncthreads();
#pragma unroll
  for (int j = 0; j < 4; ++j) {
    int r = ty + j * 8;  // local n
    float v = t[tx][r];  // element (k=k0+tx, n=n0+r)
    u16 h = f2bf(v);
    u16 l = f2bf(v - bfu(h));
    size_t o = (size_t)(blockIdx.z * N + n0 + r) * K + k0 + tx;
    Dh[o] = h;
    Dl[o] = l;
  }
}

// MFMA GEMM on pre-split hi/lo planes.
// C[M,N] = act(A @ W^T-layout + bias); A planes [M][lda], W planes [N..][ldw].
// 64x64 tile, BK=64, 256 threads = 4 waves (each 32x32 via 2x2 16x16x32 frags).
// 3 MFMAs per frag: ah*wh + al*wh + ah*wl (~2^-16 rel. accuracy).
// mode: 0 = store fp32 C, 1 = C += , 2 = store hi/lo planes Chp/Clp.
// ysplit/wrowoff1: row-block >= ysplit switches W row offset + bias to (b1,bo1).
__global__ __launch_bounds__(256) void gemm_hl(
    const u16* __restrict__ Ahp, const u16* __restrict__ Alp, int lda,
    const u16* __restrict__ Whp, const u16* __restrict__ Wlp, int ldw,
    const void* __restrict__ b0, const void* __restrict__ b1, const void* __restrict__ b2,
    size_t bo0, size_t bo1, size_t bo2, int bshift,
    float* __restrict__ C, u16* __restrict__ Chp, u16* __restrict__ Clp, int ldc,
    int K, int act, int mode, int ysplit, size_t wrowoff1,
    const int* __restrict__ dflag) {
  const int isbf = *dflag;
  __shared__ __align__(16) u16 sAh[64][72];  // 72: stride 144B = 36 banks (4 mod 32) -> optimal b128 tiling
  __shared__ __align__(16) u16 sAl[64][72];
  __shared__ __align__(16) u16 sBh[64][72];
  __shared__ __align__(16) u16 sBl[64][72];

  int tid = threadIdx.x;
  int by = blockIdx.y;
  int row0 = by * 64, col0 = blockIdx.x * 64;
  int rsplit = (by >= ysplit);
  size_t wrow0 = (size_t)col0 + (rsplit ? wrowoff1 : 0);

  int wid = tid >> 6, lane = tid & 63, quad = lane >> 4, lm = lane & 15;
  int mrow = (wid & 1) * 32, ncol = (wid >> 1) * 32;

  f32x4 acc[2][2] = {};

  int sr = tid >> 2, sc = (tid & 3) * 16;  // staging: 16 u16/thread/plane

  for (int k0 = 0; k0 < K; k0 += 64) {
    const u16* p;
    p = Ahp + (size_t)(row0 + sr) * lda + k0 + sc;
    uint4 a0 = *(const uint4*)p, a1 = *(const uint4*)(p + 8);
    p = Alp + (size_t)(row0 + sr) * lda + k0 + sc;
    uint4 a2 = *(const uint4*)p, a3 = *(const uint4*)(p + 8);
    p = Whp + (wrow0 + sr) * (size_t)ldw + k0 + sc;
    uint4 w0 = *(const uint4*)p, w1 = *(const uint4*)(p + 8);
    p = Wlp + (wrow0 + sr) * (size_t)ldw + k0 + sc;
    uint4 w2 = *(const uint4*)p, w3 = *(const uint4*)(p + 8);
    __syncthreads();  // prior iter's ds_reads done
    *(uint4*)&sAh[sr][sc] = a0; *(uint4*)&sAh[sr][sc + 8] = a1;
    *(uint4*)&sAl[sr][sc] = a2; *(uint4*)&sAl[sr][sc + 8] = a3;
    *(uint4*)&sBh[sr][sc] = w0; *(uint4*)&sBh[sr][sc + 8] = w1;
    *(uint4*)&sBl[sr][sc] = w2; *(uint4*)&sBl[sr][sc + 8] = w3;
    __syncthreads();
#pragma unroll
    for (int ks = 0; ks < 2; ++ks) {
      bf16x8 ah[2], al[2], wh[2], wl[2];
#pragma unroll
      for (int mi = 0; mi < 2; ++mi) {
        ah[mi] = *(const bf16x8*)&sAh[mrow + mi * 16 + lm][ks * 32 + quad * 8];
        al[mi] = *(const bf16x8*)&sAl[mrow + mi * 16 + lm][ks * 32 + quad * 8];
      }
#pragma unroll
      for (int ni = 0; ni < 2; ++ni) {
        wh[ni] = *(const bf16x8*)&sBh[ncol + ni * 16 + lm][ks * 32 + quad * 8];
        wl[ni] = *(const bf16x8*)&sBl[ncol + ni * 16 + lm][ks * 32 + quad * 8];
      }
#pragma unroll
      for (int mi = 0; mi < 2; ++mi)
#pragma unroll
        for (int ni = 0; ni < 2; ++ni) {
          acc[mi][ni] = __builtin_amdgcn_mfma_f32_16x16x32_bf16(ah[mi], wh[ni], acc[mi][ni], 0, 0, 0);
          acc[mi][ni] = __builtin_amdgcn_mfma_f32_16x16x32_bf16(al[mi], wh[ni], acc[mi][ni], 0, 0, 0);
          acc[mi][ni] = __builtin_amdgcn_mfma_f32_16x16x32_bf16(ah[mi], wl[ni], acc[mi][ni], 0, 0, 0);
        }
    }
  }
  // C/D layout: col=lane&15, row=quad*4+reg (m89-verified)
#pragma unroll
  for (int mi = 0; mi < 2; ++mi) {
#pragma unroll
    for (int ni = 0; ni < 2; ++ni) {
      int colg = col0 + ncol + ni * 16 + lm;
      const void* bp; size_t bo;
      if (rsplit) { bp = b1; bo = bo1; }
      else {
        int seg = colg >> bshift;
        bp = (seg == 0) ? b0 : ((seg == 1) ? b1 : b2);
        bo = (seg == 0) ? bo0 : ((seg == 1) ? bo1 : bo2);
        bo += (size_t)colg - ((size_t)seg << bshift);
        goto have;
      }
      bo += colg;
    have:;
      float bv = ldin(bp, bo, isbf);
#pragma unroll
      for (int r = 0; r < 4; ++r) {
        int rowg = row0 + mrow + mi * 16 + quad * 4 + r;
        float v = acc[mi][ni][r] + bv;
        if (act) v = v * 0.5f * (1.f + erff(v * 0.70710678118654752f));
        size_t o = (size_t)rowg * ldc + colg;
        if (mode == 0) C[o] = v;
        else if (mode == 1) C[o] += v;
        else {
          u16 h = f2bf(v);
          Chp[o] = h;
          Clp[o] = f2bf(v - bfu(h));
        }
      }
    }
  }
}

// emb+pos LN, both encoders (1024 rows): writes fp32 x AND hi/lo planes.
__global__ __launch_bounds__(256) void emb_ln2(
    const void* __restrict__ qe, const void* __restrict__ ae, const void* __restrict__ pos,
    const void* __restrict__ w, const void* __restrict__ b,
    float* __restrict__ x, u16* __restrict__ oh, u16* __restrict__ ol,
    const int* __restrict__ dflag) {
  const int isbf = *dflag;
  const int D = 512;
  int row = blockIdx.x;
  const void* emb = (row < 512) ? qe : ae;
  int lr = row & 511, t = row & 127;
  __shared__ float sbuf[8];
  int i0 = threadIdx.x, i1 = threadIdx.x + 256;
  float v0 = ldin(emb, (size_t)lr * D + i0, isbf) + ldin(pos, (size_t)t * D + i0, isbf);
  float v1 = ldin(emb, (size_t)lr * D + i1, isbf) + ldin(pos, (size_t)t * D + i1, isbf);
  float mean = block_sum(v0 + v1, sbuf) / 512.f;
  float d0 = v0 - mean, d1 = v1 - mean;
  float var = block_sum(d0 * d0 + d1 * d1, sbuf) / 512.f;
  float inv = 1.0f / sqrtf(var + 1e-12f);
  float r0 = ldin(w, i0, isbf) * d0 * inv + ldin(b, i0, isbf);
  float r1 = ldin(w, i1, isbf) * d1 * inv + ldin(b, i1, isbf);
  size_t o0 = (size_t)row * D + i0, o1 = (size_t)row * D + i1;
  x[o0] = r0; x[o1] = r1;
  u16 h0 = f2bf(r0); oh[o0] = h0; ol[o0] = f2bf(r0 - bfu(h0));
  u16 h1 = f2bf(r1); oh[o1] = h1; ol[o1] = f2bf(r1 - bfu(h1));
}

// LN fp32 in -> optional fp32 out (in-place safe) + hi/lo planes.
__global__ __launch_bounds__(256) void ln2(
    const float* __restrict__ in, float* __restrict__ outf,
    u16* __restrict__ oh, u16* __restrict__ ol,
    const void* __restrict__ w, const void* __restrict__ b, size_t wboff,
    const int* __restrict__ dflag) {
  const int isbf = *dflag;
  const int D = 512;
  int row = blockIdx.x;
  __shared__ float sbuf[8];
  int i0 = threadIdx.x, i1 = threadIdx.x + 256;
  float v0 = in[(size_t)row * D + i0];
  float v1 = in[(size_t)row * D + i1];
  float mean = block_sum(v0 + v1, sbuf) / 512.f;
  float d0 = v0 - mean, d1 = v1 - mean;
  float var = block_sum(d0 * d0 + d1 * d1, sbuf) / 512.f;
  float inv = 1.0f / sqrtf(var + 1e-12f);
  float r0 = ldin(w, wboff + i0, isbf) * d0 * inv + ldin(b, wboff + i0, isbf);
  float r1 = ldin(w, wboff + i1, isbf) * d1 * inv + ldin(b, wboff + i1, isbf);
  size_t o0 = (size_t)row * D + i0, o1 = (size_t)row * D + i1;
  if (outf) { outf[o0] = r0; outf[o1] = r1; }
  u16 h0 = f2bf(r0); oh[o0] = h0; ol[o0] = f2bf(r0 - bfu(h0));
  u16 h1 = f2bf(r1); oh[o1] = h1; ol[o1] = f2bf(r1 - bfu(h1));
}

// MHA attention, batched encoders: qkv [1024][1536] fp32 -> hi/lo planes [1024][512].
__global__ __launch_bounds__(128) void attn2(const float* __restrict__ qkv,
                                             u16* __restrict__ oh, u16* __restrict__ ol) {
  int t = blockIdx.x & 127;
  int h = (blockIdx.x >> 7) & 3;
  int g = blockIdx.x >> 9;  // 0..7 = (enc*4+b)
  int tid = threadIdx.x;
  const float* base = qkv + (size_t)g * 128 * 1536;
  __shared__ float qs[128];
  __shared__ float ps[128];
  __shared__ float sbuf[8];
  qs[tid] = base[(size_t)t * 1536 + h * 128 + tid];
  __syncthreads();
  const float* krow = base + (size_t)tid * 1536 + 512 + h * 128;
  float sc = 0.f;
#pragma unroll
  for (int d = 0; d < 128; d += 4) {
    float4 kv4 = *(const float4*)(krow + d);
    sc = fmaf(qs[d], kv4.x, sc);
    sc = fmaf(qs[d + 1], kv4.y, sc);
    sc = fmaf(qs[d + 2], kv4.z, sc);
    sc = fmaf(qs[d + 3], kv4.w, sc);
  }
  sc *= 0.08838834764831845f;  // 1/sqrt(128)
  float mx = block_max(sc, sbuf);
  float e = expf(sc - mx);
  float s = block_sum(e, sbuf);
  ps[tid] = e / s;
  __syncthreads();
  float acc = 0.f;
  const float* vcol = base + 1024 + h * 128 + tid;
  for (int s2 = 0; s2 < 128; ++s2)
    acc = fmaf(ps[s2], vcol[(size_t)s2 * 1536], acc);
  size_t o = (size_t)(g * 128 + t) * 512 + h * 128 + tid;
  u16 hh = f2bf(acc);
  oh[o] = hh;
  ol[o] = f2bf(acc - bfu(hh));
}

// ===========================================================================
// head kernels (shared by both paths) + fallback round-6 kernels
// ===========================================================================

__global__ __launch_bounds__(64) void proj_ce_kernel(const float* __restrict__ q,
                                                     const void* __restrict__ ce,
                                                     float* __restrict__ out, int D, int NC,
                                                     const int* __restrict__ dflag) {
  const int isbf = *dflag;
  int row = blockIdx.x;
  for (int c = 0; c < NC; ++c) {
    float acc = 0.f;
    for (int d = threadIdx.x; d < D; d += 64)
      acc = fmaf(q[(size_t)row * D + d], ldin(ce, (size_t)c * D + d, isbf), acc);
    acc = wave_sum(acc);
    if (threadIdx.x == 0) out[row * NC + c] = acc;
  }
}

__global__ __launch_bounds__(64) void gram_kernel(const void* __restrict__ ce,
                                                  float* __restrict__ G, int D, int NC,
                                                  const int* __restrict__ dflag) {
  const int isbf = *dflag;
  int c = blockIdx.x / NC, c2 = blockIdx.x % NC;
  float acc = 0.f;
  for (int d = threadIdx.x; d < D; d += 64)
    acc = fmaf(ldin(ce, (size_t)c * D + d, isbf), ldin(ce, (size_t)c2 * D + d, isbf), acc);
  acc = wave_sum(acc);
  if (threadIdx.x == 0) G[blockIdx.x] = acc;
}

__global__ __launch_bounds__(128) void sim_scores_kernel(
    const float* __restrict__ q, const float* __restrict__ k, const void* __restrict__ qa,
    const void* __restrict__ aq, const float* __restrict__ qc, const float* __restrict__ kc,
    const float* __restrict__ G, float* __restrict__ p_out, float* __restrict__ pa_out,
    int B, int T1, int T2, int D, int NC, const int* __restrict__ dflag) {
  const int isbf = *dflag;
  int t = blockIdx.x % T1;
  int b = blockIdx.x / T1;
  int s = threadIdx.x;
  __shared__ float qs[512];
  __shared__ float Gs[25];
  __shared__ float qcs[5];
  __shared__ float sbuf[8];
  for (int i = threadIdx.x; i < D; i += 128) qs[i] = q[(size_t)(b * T1 + t) * D + i];
  if (threadIdx.x < NC * NC) Gs[threadIdx.x] = G[threadIdx.x];
  if (threadIdx.x < NC) qcs[threadIdx.x] = qc[(b * T1 + t) * NC + threadIdx.x];
  __syncthreads();
  const float* krow = k + (size_t)(b * T2 + s) * D;
  float sc = 0.f;
#pragma unroll 8
  for (int d = 0; d < 512; ++d) sc = fmaf(qs[d], krow[d], sc);
  float qav[5], aqv[5];
#pragma unroll
  for (int c = 0; c < 5; ++c) {
    qav[c] = ldin(qa, (size_t)((b * T1 + t) * T2 + s) * NC + c, isbf);
    aqv[c] = ldin(aq, (size_t)((b * T2 + s) * T1 + t) * NC + c, isbf);
  }
#pragma unroll
  for (int c = 0; c < 5; ++c) {
    sc = fmaf(aqv[c], qcs[c], sc);
    sc = fmaf(qav[c], kc[(b * T2 + s) * NC + c], sc);
#pragma unroll
    for (int c2 = 0; c2 < 5; ++c2) sc = fmaf(qav[c] * Gs[c * 5 + c2], aqv[c2], sc);
  }
  float mx = block_max(sc, sbuf);
  float e = expf(sc - mx);
  float ssum = block_sum(e, sbuf);
  float p = e / ssum;
  float mx2 = block_max(p, sbuf);
  float e2 = expf(1000.f * (p - mx2));
  float s2 = block_sum(e2, sbuf);
  float pf = fminf(fmaxf(e2 / s2, 0.f), 1.f);
  p_out[(size_t)(b * T1 + t) * T2 + s] = pf;
#pragma unroll
  for (int c = 0; c < 5; ++c) {
    float pc = block_sum(pf * aqv[c], sbuf);
    if (threadIdx.x == 0) pa_out[(b * T1 + t) * NC + c] = pc;
  }
}

__global__ __launch_bounds__(512) void sim_x_kernel(const float* __restrict__ p, const float* __restrict__ k,
                                                    const float* __restrict__ pa,
                                                    const void* __restrict__ ce,
                                                    float* __restrict__ x, int B, int T1, int T2, int D, int NC,
                                                    const int* __restrict__ dflag) {
  const int isbf = *dflag;
  int t = blockIdx.x % T1;
  int b = blockIdx.x / T1;
  int d = threadIdx.x;
  __shared__ float ps[128];
  __shared__ float pav[5];
  if (threadIdx.x < T2) ps[threadIdx.x] = p[(size_t)(b * T1 + t) * T2 + threadIdx.x];
  if (threadIdx.x < NC) pav[threadIdx.x] = pa[(b * T1 + t) * NC + threadIdx.x];
  __syncthreads();
  float acc = 0.f;
  for (int s = 0; s < 128; ++s) acc = fmaf(ps[s], k[(size_t)(b * T2 + s) * D + d], acc);
#pragma unroll
  for (int c = 0; c < 5; ++c) acc = fmaf(pav[c], ldin(ce, (size_t)c * D + d, isbf), acc);
  x[(size_t)(b * T1 + t) * D + d] = acc;
}

__global__ __launch_bounds__(512) void mean_kernel(const float* __restrict__ x, float* __restrict__ xm,
                                                   int T, int D) {
  int b = blockIdx.x;
  int d = threadIdx.x;
  float acc = 0.f;
  for (int t = 0; t < T; ++t) acc += x[(size_t)(b * T + t) * D + d];
  xm[(size_t)b * D + d] = acc / (float)T;
}

__global__ __launch_bounds__(64) void cls_kernel(const float* __restrict__ xm,
                                                 const void* __restrict__ w,
                                                 const void* __restrict__ bias,
                                                 void* __restrict__ out, int D, int NO,
                                                 const int* __restrict__ dflag) {
  const int isbf = *dflag;
  int j = blockIdx.x % NO;
  int b = blockIdx.x / NO;
  float acc = 0.f;
  for (int d = threadIdx.x; d < D; d += 64)
    acc = fmaf(xm[(size_t)b * D + d], ldin(w, (size_t)d * NO + j, isbf), acc);
  acc = wave_sum(acc);
  if (threadIdx.x == 0) {
    float val = acc + ldin(bias, j, isbf);
    if (isbf) ((__hip_bfloat16*)out)[b * NO + j] = __float2bfloat16(val);
    else ((float*)out)[b * NO + j] = val;
  }
}

// ---- round-6 fallback kernels (used only if ws too small for fast path) ----

__global__ __launch_bounds__(256) void gemm_mfma(
    const float* __restrict__ A, const void* __restrict__ W, size_t woff,
    const void* __restrict__ bias, size_t boff,
    float* __restrict__ C, int M, int N, int K, int act, int addto,
    const int* __restrict__ dflag) {
  const int isbf = *dflag;
  __shared__ __align__(16) u16 Ah[64][40];
  __shared__ __align__(16) u16 Al[64][40];
  __shared__ __align__(16) u16 Wh[64][40];
  __shared__ __align__(16) u16 Wl[64][40];
  int tid = threadIdx.x;
  int row0 = blockIdx.y * 64, col0 = blockIdx.x * 64;
  int wid = tid >> 6, lane = tid & 63;
  int quad = lane >> 4, lm = lane & 15;
  int mrow = (wid & 1) * 32, ncol = (wid >> 1) * 32;
  f32x4 acc[2][2] = {};
  int ar = tid >> 2, akc = (tid & 3) * 8;
  int bk = tid >> 3, bn0 = (tid & 7) * 8;
  for (int k0 = 0; k0 < K; k0 += 32) {
    const float* ap = A + (size_t)(row0 + ar) * K + k0 + akc;
    float av[8];
    *(float4*)(av) = *(const float4*)ap;
    *(float4*)(av + 4) = *(const float4*)(ap + 4);
    unsigned hp[4], lp[4];
#pragma unroll
    for (int j = 0; j < 4; ++j) {
      u16 h0 = f2bf(av[2 * j]);
      u16 h1 = f2bf(av[2 * j + 1]);
      u16 l0 = f2bf(av[2 * j] - bfu(h0));
      u16 l1 = f2bf(av[2 * j + 1] - bfu(h1));
      hp[j] = (unsigned)h0 | ((unsigned)h1 << 16);
      lp[j] = (unsigned)l0 | ((unsigned)l1 << 16);
    }
    *(uint4*)&Ah[ar][akc] = make_uint4(hp[0], hp[1], hp[2], hp[3]);
    *(uint4*)&Al[ar][akc] = make_uint4(lp[0], lp[1], lp[2], lp[3]);
    float wv[8];
    size_t welem = woff + (size_t)(k0 + bk) * N + col0 + bn0;
    if (isbf) {
      const u16* wp = (const u16*)W + welem;
      uint4 raw = *(const uint4*)wp;
      wv[0] = bfu((u16)(raw.x & 0xFFFF)); wv[1] = bfu((u16)(raw.x >> 16));
      wv[2] = bfu((u16)(raw.y & 0xFFFF)); wv[3] = bfu((u16)(raw.y >> 16));
      wv[4] = bfu((u16)(raw.z & 0xFFFF)); wv[5] = bfu((u16)(raw.z >> 16));
      wv[6] = bfu((u16)(raw.w & 0xFFFF)); wv[7] = bfu((u16)(raw.w >> 16));
    } else {
      const float* wp = (const float*)W + welem;
      *(float4*)(wv) = *(const float4*)wp;
      *(float4*)(wv + 4) = *(const float4*)(wp + 4);
    }
#pragma unroll
    for (int i = 0; i < 8; ++i) {
      u16 h = f2bf(wv[i]);
      u16 l = f2bf(wv[i] - bfu(h));
      Wh[bn0 + i][bk] = h;
      Wl[bn0 + i][bk] = l;
    }
    __syncthreads();
#pragma unroll
    for (int mi = 0; mi < 2; ++mi) {
      bf16x8 ah = *(const bf16x8*)&Ah[mrow + mi * 16 + lm][quad * 8];
      bf16x8 al = *(const bf16x8*)&Al[mrow + mi * 16 + lm][quad * 8];
#pragma unroll
      for (int ni = 0; ni < 2; ++ni) {
        bf16x8 wh = *(const bf16x8*)&Wh[ncol + ni * 16 + lm][quad * 8];
        bf16x8 wl = *(const bf16x8*)&Wl[ncol + ni * 16 + lm][quad * 8];
        acc[mi][ni] = __builtin_amdgcn_mfma_f32_16x16x32_bf16(ah, wh, acc[mi][ni], 0, 0, 0);
        acc[mi][ni] = __builtin_amdgcn_mfma_f32_16x16x32_bf16(al, wh, acc[mi][ni], 0, 0, 0);
        acc[mi][ni] = __builtin_amdgcn_mfma_f32_16x16x32_bf16(ah, wl, acc[mi][ni], 0, 0, 0);
      }
    }
    __syncthreads();
  }
#pragma unroll
  for (int mi = 0; mi < 2; ++mi) {
#pragma unroll
    for (int ni = 0; ni < 2; ++ni) {
      int colg = col0 + ncol + ni * 16 + lm;
      float bv = ldin(bias, boff + colg, isbf);
#pragma unroll
      for (int r = 0; r < 4; ++r) {
        int rowg = row0 + mrow + mi * 16 + quad * 4 + r;
        float v = acc[mi][ni][r] + bv;
        if (act) v = v * 0.5f * (1.f + erff(v * 0.70710678118654752f));
        size_t o = (size_t)rowg * N + colg;
        if (addto) C[o] += v; else C[o] = v;
      }
    }
  }
}

__global__ __launch_bounds__(256) void emb_ln_kernel(const void* __restrict__ emb,
                                                     const void* __restrict__ pos,
                                                     const void* __restrict__ w,
                                                     const void* __restrict__ b,
                                                     float* __restrict__ out, int T, int D,
                                                     const int* __restrict__ dflag) {
  const int isbf = *dflag;
  int row = blockIdx.x;
  int t = row % T;
  __shared__ float sbuf[8];
  int i0 = threadIdx.x, i1 = threadIdx.x + 256;
  float v0 = ldin(emb, (size_t)row * D + i0, isbf) + ldin(pos, (size_t)t * D + i0, isbf);
  float v1 = ldin(emb, (size_t)row * D + i1, isbf) + ldin(pos, (size_t)t * D + i1, isbf);
  float mean = block_sum(v0 + v1, sbuf) / (float)D;
  float d0 = v0 - mean, d1 = v1 - mean;
  float var = block_sum(d0 * d0 + d1 * d1, sbuf) / (float)D;
  float inv = 1.0f / sqrtf(var + 1e-12f);
  out[(size_t)row * D + i0] = ldin(w, i0, isbf) * d0 * inv + ldin(b, i0, isbf);
  out[(size_t)row * D + i1] = ldin(w, i1, isbf) * d1 * inv + ldin(b, i1, isbf);
}

__global__ __launch_bounds__(256) void ln_kernel(const float* __restrict__ in, float* __restrict__ out,
                                                 const void* __restrict__ w, const void* __restrict__ b,
                                                 size_t wboff, int D, const int* __restrict__ dflag) {
  const int isbf = *dflag;
  int row = blockIdx.x;
  __shared__ float sbuf[8];
  int i0 = threadIdx.x, i1 = threadIdx.x + 256;
  float v0 = in[(size_t)row * D + i0];
  float v1 = in[(size_t)row * D + i1];
  float mean = block_sum(v0 + v1, sbuf) / (float)D;
  float d0 = v0 - mean, d1 = v1 - mean;
  float var = block_sum(d0 * d0 + d1 * d1, sbuf) / (float)D;
  float inv = 1.0f / sqrtf(var + 1e-12f);
  out[(size_t)row * D + i0] = ldin(w, wboff + i0, isbf) * d0 * inv + ldin(b, wboff + i0, isbf);
  out[(size_t)row * D + i1] = ldin(w, wboff + i1, isbf) * d1 * inv + ldin(b, wboff + i1, isbf);
}

__global__ __launch_bounds__(128) void attn_kernel(const float* __restrict__ q, const float* __restrict__ k,
                                                   const float* __restrict__ v, float* __restrict__ o,
                                                   int B, int H, int T, int dk) {
  int t = blockIdx.x % T;
  int h = (blockIdx.x / T) % H;
  int b = blockIdx.x / (T * H);
  int D = H * dk;
  int tid = threadIdx.x;
  __shared__ float qs[128];
  __shared__ float ps[128];
  __shared__ float sbuf[8];
  qs[tid] = q[(size_t)(b * T + t) * D + h * dk + tid];
  __syncthreads();
  const float* krow = k + (size_t)(b * T + tid) * D + h * dk;
  float sc = 0.f;
#pragma unroll 8
  for (int d = 0; d < 128; ++d) sc = fmaf(qs[d], krow[d], sc);
  sc *= 0.08838834764831845f;
  float mx = block_max(sc, sbuf);
  float e = expf(sc - mx);
  float s = block_sum(e, sbuf);
  ps[tid] = e / s;
  __syncthreads();
  float acc = 0.f;
  for (int s2 = 0; s2 < 128; ++s2)
    acc = fmaf(ps[s2], v[(size_t)(b * T + s2) * D + h * dk + tid], acc);
  o[(size_t)(b * T + t) * D + h * dk + tid] = acc;
}

// ===========================================================================
extern "C" void kernel_launch(void* const* d_in, const int* in_sizes, int n_in,
                              void* d_out, int out_size, void* d_ws, size_t ws_size,
                              hipStream_t stream) {
  const int B = 4, T = 128, D = 512, H = 4, NL = 4, DFF = 2048, NC = 5;
  const void *q_emb = d_in[0], *a_emb = d_in[1], *qa = d_in[2], *aqr = d_in[3],
             *ce = d_in[4], *pos = d_in[5], *pe_w = d_in[6], *pe_b = d_in[7],
             *Wq = d_in[8], *bq = d_in[9], *Wk = d_in[10], *bk = d_in[11],
             *Wv = d_in[12], *bv = d_in[13], *Wo = d_in[14], *bo = d_in[15],
             *ff1w = d_in[16], *ff1b = d_in[17], *ff2w = d_in[18], *ff2b = d_in[19],
             *lnin_w = d_in[20], *lnin_b = d_in[21], *lnout_w = d_in[22], *lnout_b = d_in[23],
             *simWq = d_in[24], *simbq = d_in[25], *simWk = d_in[26], *simbk = d_in[27],
             *clsw = d_in[28], *clsb = d_in[29];

  const size_t REQ = 23100000ull;
  if (ws_size >= REQ) {
    // -------- FAST PATH --------
    char* base = (char*)d_ws;
    float* x = (float*)(base + 0);                 // [1024][512] fp32 (2 MB)
    u16* xch = (u16*)(base + 2097152);             // [1024][512] hi (1 MB)
    u16* xcl = (u16*)(base + 3145728);             // lo (1 MB)
    float* qkv = (float*)(base + 4194304);         // [1024][1536] fp32 (6 MB)
    u16* ffch = (u16*)(base + 10485760);           // [1024][2048] hi (4 MB)
    u16* ffcl = (u16*)(base + 14680064);           // lo (4 MB)
    u16* wth = (u16*)(base + 18874368);            // weight hi plane (2 MB)
    u16* wtl = (u16*)(base + 20971520);            // weight lo plane (2 MB)
    int* dflag = (int*)(base + 23068672);
    // sim overlays inside qkv region (dead then)
    float* qkb = (float*)(base + 4194304);         // [1024][512] fp32
    float* pbuf = (float*)(base + 6291456);
    float* pabuf = (float*)(base + 6553600);
    float* qcbuf = (float*)(base + 6563840);
    float* kcbuf = (float*)(base + 6574080);
    float* Gbuf = (float*)(base + 6584320);
    float* xmean = (float*)(base + 6584448);
    float* xsim = (float*)(base + 6592640);

    flag_kernel<<<1, 64, 0, stream>>>(pe_w, dflag);
    emb_ln2<<<1024, 256, 0, stream>>>(q_emb, a_emb, pos, pe_w, pe_b, x, xch, xcl, dflag);

    for (int l = 0; l < NL; ++l) {
      size_t wDD = (size_t)l * D * D, bD = (size_t)l * D;
      // QKV (fused): wt = [1536][512]
      convT<<<dim3(16, 16, 3), 256, 0, stream>>>(Wq, Wk, Wv, wDD, 512, 512, wth, wtl, dflag);
      gemm_hl<<<dim3(24, 16), 256, 0, stream>>>(xch, xcl, 512, wth, wtl, 512,
                                                bq, bk, bv, bD, bD, bD, 9,
                                                qkv, nullptr, nullptr, 1536,
                                                512, 0, 0, 9999, 0, dflag);
      attn2<<<4096, 128, 0, stream>>>(qkv, xch, xcl);
      // O-proj
      convT<<<dim3(16, 16, 1), 256, 0, stream>>>(Wo, Wo, Wo, wDD, 512, 512, wth, wtl, dflag);
      gemm_hl<<<dim3(8, 16), 256, 0, stream>>>(xch, xcl, 512, wth, wtl, 512,
                                               bo, bo, bo, bD, bD, bD, 9,
                                               x, nullptr, nullptr, 512,
                                               512, 0, 1, 9999, 0, dflag);
      ln2<<<1024, 256, 0, stream>>>(x, nullptr, xch, xcl, lnin_w, lnin_b, bD, dflag);
      // FF1: wt = [2048][512]
      convT<<<dim3(64, 16, 1), 256, 0, stream>>>(ff1w, ff1w, ff1w, (size_t)l * D * DFF,
                                                 512, 2048, wth, wtl, dflag);
      gemm_hl<<<dim3(32, 16), 256, 0, stream>>>(xch, xcl, 512, wth, wtl, 512,
                                                ff1b, ff1b, ff1b,
                                                (size_t)l * DFF, (size_t)l * DFF, (size_t)l * DFF, 11,
                                                nullptr, ffch, ffcl, 2048,
                                                512, 1, 2, 9999, 0, dflag);
      // FF2: wt = [512][2048]
      convT<<<dim3(16, 64, 1), 256, 0, stream>>>(ff2w, ff2w, ff2w, (size_t)l * DFF * D,
                                                 2048, 512, wth, wtl, dflag);
      gemm_hl<<<dim3(8, 16), 256, 0, stream>>>(ffch, ffcl, 2048, wth, wtl, 2048,
                                               ff2b, ff2b, ff2b, bD, bD, bD, 9,
                                               x, nullptr, nullptr, 512,
                                               2048, 0, 1, 9999, 0, dflag);
      ln2<<<1024, 256, 0, stream>>>(x, x, xch, xcl, lnout_w, lnout_b, bD, dflag);
    }

    // Sim head: one fused GEMM (rows 0-511 = q enc * simWq; rows 512-1023 = a enc * simWk)
    convT<<<dim3(16, 16, 2), 256, 0, stream>>>(simWq, simWk, simWk, 0, 512, 512, wth, wtl, dflag);
    gemm_hl<<<dim3(8, 16), 256, 0, stream>>>(xch, xcl, 512, wth, wtl, 512,
                                             simbq, simbk, simbk, 0, 0, 0, 9,
                                             qkb, nullptr, nullptr, 512,
                                             512, 0, 0, 8, 512, dflag);
    float* qb = qkb;
    float* kb = qkb + (size_t)512 * 512;
    proj_ce_kernel<<<512, 64, 0, stream>>>(qb, ce, qcbuf, D, NC, dflag);
    proj_ce_kernel<<<512, 64, 0, stream>>>(kb, ce, kcbuf, D, NC, dflag);
    gram_kernel<<<25, 64, 0, stream>>>(ce, Gbuf, D, NC, dflag);
    sim_scores_kernel<<<512, 128, 0, stream>>>(qb, kb, qa, aqr, qcbuf, kcbuf, Gbuf, pbuf, pabuf,
                                               B, T, T, D, NC, dflag);
    sim_x_kernel<<<512, 512, 0, stream>>>(pbuf, kb, pabuf, ce, xsim, B, T, T, D, NC, dflag);
    mean_kernel<<<4, 512, 0, stream>>>(xsim, xmean, T, D);
    cls_kernel<<<12, 64, 0, stream>>>(xmean, clsw, clsb, d_out, D, 3, dflag);
    return;
  }

  // -------- FALLBACK: round-6 passing path --------
  float* ws = (float*)d_ws;
  const size_t S = (size_t)512 * 512;
  float* qe = ws;
  float* ae = ws + S;
  float* hb = ws + 2 * S;
  float* rb = ws + 3 * S;
  float* qb = rb;
  float* kb = rb + S;
  float* vb = rb + 2 * S;
  float* ob = rb + 3 * S;
  float* ffb = rb;
  float* pbuf = rb + 2 * S;
  float* pabuf = pbuf + 65536;
  float* qcbuf = pabuf + 2560;
  float* kcbuf = qcbuf + 2560;
  float* Gbuf = kcbuf + 2560;
  float* xmean = Gbuf + 32;
  float* xsim = rb + 3 * S;
  int* dflag = (int*)(ws + 7 * S);

  const int M = B * T;
  dim3 gD(8, 8), gF1(32, 8), gF2(8, 8);

  flag_kernel<<<1, 64, 0, stream>>>(pe_w, dflag);
  for (int e = 0; e < 2; ++e) {
    float* x = (e == 0) ? qe : ae;
    const void* emb = (e == 0) ? q_emb : a_emb;
    emb_ln_kernel<<<M, 256, 0, stream>>>(emb, pos, pe_w, pe_b, x, T, D, dflag);
    for (int l = 0; l < NL; ++l) {
      size_t wDD = (size_t)l * D * D, bD = (size_t)l * D;
      gemm_mfma<<<gD, 256, 0, stream>>>(x, Wq, wDD, bq, bD, qb, M, D, D, 0, 0, dflag);
      gemm_mfma<<<gD, 256, 0, stream>>>(x, Wk, wDD, bk, bD, kb, M, D, D, 0, 0, dflag);
      gemm_mfma<<<gD, 256, 0, stream>>>(x, Wv, wDD, bv, bD, vb, M, D, D, 0, 0, dflag);
      attn_kernel<<<B * H * T, 128, 0, stream>>>(qb, kb, vb, ob, B, H, T, D / H);
      gemm_mfma<<<gD, 256, 0, stream>>>(ob, Wo, wDD, bo, bD, x, M, D, D, 0, 1, dflag);
      ln_kernel<<<M, 256, 0, stream>>>(x, hb, lnin_w, lnin_b, bD, D, dflag);
      gemm_mfma<<<gF1, 256, 0, stream>>>(hb, ff1w, (size_t)l * D * DFF, ff1b, (size_t)l * DFF,
                                         ffb, M, DFF, D, 1, 0, dflag);
      gemm_mfma<<<gF2, 256, 0, stream>>>(ffb, ff2w, (size_t)l * DFF * D, ff2b, bD,
                                         x, M, D, DFF, 0, 1, dflag);
      ln_kernel<<<M, 256, 0, stream>>>(x, x, lnout_w, lnout_b, bD, D, dflag);
    }
  }
  gemm_mfma<<<gD, 256, 0, stream>>>(qe, simWq, 0, simbq, 0, qb, M, D, D, 0, 0, dflag);
  gemm_mfma<<<gD, 256, 0, stream>>>(ae, simWk, 0, simbk, 0, kb, M, D, D, 0, 0, dflag);
  proj_ce_kernel<<<M, 64, 0, stream>>>(qb, ce, qcbuf, D, NC, dflag);
  proj_ce_kernel<<<M, 64, 0, stream>>>(kb, ce, kcbuf, D, NC, dflag);
  gram_kernel<<<NC * NC, 64, 0, stream>>>(ce, Gbuf, D, NC, dflag);
  sim_scores_kernel<<<B * T, 128, 0, stream>>>(qb, kb, qa, aqr, qcbuf, kcbuf, Gbuf, pbuf, pabuf,
                                               B, T, T, D, NC, dflag);
  sim_x_kernel<<<B * T, 512, 0, stream>>>(pbuf, kb, pabuf, ce, xsim, B, T, T, D, NC, dflag);
  mean_kernel<<<B, 512, 0, stream>>>(xsim, xmean, T, D);
  cls_kernel<<<B * 3, 64, 0, stream>>>(xmean, clsw, clsb, d_out, D, 3, dflag);
}

// Round 8
// 757.234 us; speedup vs baseline: 4.2949x; 1.1876x over previous
//
#include <hip/hip_runtime.h>
#include <hip/hip_bf16.h>
#include <math.h>

typedef unsigned short u16;
typedef __attribute__((ext_vector_type(8))) short bf16x8;   // 8 bf16 (4 VGPRs)
typedef __attribute__((ext_vector_type(4))) float f32x4;

// Inputs may be bf16 or fp32; device flag (pe_w all-ones: first u16 0x3F80 iff
// bf16, 0x0000 iff fp32 1.0f). r1-r6 evidence: inputs are fp32, but keep flag.
__device__ __forceinline__ float ldin(const void* p, size_t i, int isbf) {
  if (isbf) return __bfloat162float(((const __hip_bfloat16*)p)[i]);
  return ((const float*)p)[i];
}
__device__ __forceinline__ float bfu(u16 u) { return __builtin_bit_cast(float, (unsigned)u << 16); }
__device__ __forceinline__ u16 f2bf(float x) {  // round-to-nearest-even
  unsigned u = __builtin_bit_cast(unsigned, x);
  unsigned r = u + 0x7FFFu + ((u >> 16) & 1u);
  return (u16)(r >> 16);
}

__device__ __forceinline__ float wave_sum(float v) {
#pragma unroll
  for (int o = 32; o > 0; o >>= 1) v += __shfl_down(v, o);
  return v;
}

__device__ __forceinline__ float block_sum(float v, float* sbuf) {
  int lane = threadIdx.x & 63;
  int wid = threadIdx.x >> 6;
#pragma unroll
  for (int o = 32; o > 0; o >>= 1) v += __shfl_down(v, o);
  __syncthreads();
  if (lane == 0) sbuf[wid] = v;
  __syncthreads();
  int nw = blockDim.x >> 6;
  if (wid == 0) {
    float r = (lane < nw) ? sbuf[lane] : 0.f;
#pragma unroll
    for (int o = 4; o > 0; o >>= 1) r += __shfl_down(r, o);
    if (lane == 0) sbuf[0] = r;
  }
  __syncthreads();
  return sbuf[0];
}

__device__ __forceinline__ float block_max(float v, float* sbuf) {
  int lane = threadIdx.x & 63;
  int wid = threadIdx.x >> 6;
#pragma unroll
  for (int o = 32; o > 0; o >>= 1) v = fmaxf(v, __shfl_down(v, o));
  __syncthreads();
  if (lane == 0) sbuf[wid] = v;
  __syncthreads();
  int nw = blockDim.x >> 6;
  if (wid == 0) {
    float r = (lane < nw) ? sbuf[lane] : -INFINITY;
#pragma unroll
    for (int o = 4; o > 0; o >>= 1) r = fmaxf(r, __shfl_down(r, o));
    if (lane == 0) sbuf[0] = r;
  }
  __syncthreads();
  return sbuf[0];
}

__global__ void flag_kernel(const void* pe_w, int* flag) {
  if (threadIdx.x == 0 && blockIdx.x == 0)
    *flag = (((const unsigned short*)pe_w)[0] != 0) ? 1 : 0;
}

// ===========================================================================
// FAST PATH kernels
// ===========================================================================

// Weight convert+transpose: src [K][N] (flag dtype, up to 4 z-segments) ->
// dst hi/lo u16 planes [nseg*N][K]. 32x32 LDS tile, 256 threads.
__global__ __launch_bounds__(256) void convT(
    const void* __restrict__ S0, const void* __restrict__ S1,
    const void* __restrict__ S2, const void* __restrict__ S3,
    size_t woff, int K, int N, u16* __restrict__ Dh, u16* __restrict__ Dl,
    const int* __restrict__ dflag) {
  const int isbf = *dflag;
  const void* S = (blockIdx.z == 0) ? S0 : ((blockIdx.z == 1) ? S1 : ((blockIdx.z == 2) ? S2 : S3));
  int n0 = blockIdx.x * 32, k0 = blockIdx.y * 32;
  __shared__ float t[32][33];
  int tx = threadIdx.x & 31, ty = threadIdx.x >> 5;
#pragma unroll
  for (int j = 0; j < 4; ++j) {
    int r = ty + j * 8;  // local k
    t[r][tx] = ldin(S, woff + (size_t)(k0 + r) * N + n0 + tx, isbf);
  }
  __syncthreads();
#pragma unroll
  for (int j = 0; j < 4; ++j) {
    int r = ty + j * 8;  // local n
    float v = t[tx][r];  // element (k=k0+tx, n=n0+r)
    u16 h = f2bf(v);
    u16 l = f2bf(v - bfu(h));
    size_t o = (size_t)(blockIdx.z * N + n0 + r) * K + k0 + tx;
    Dh[o] = h;
    Dl[o] = l;
  }
}

// MFMA GEMM on pre-split hi/lo planes.
// 64x64 tile, BK=64, 256 threads = 4 waves. 3 MFMAs/frag (ah*wh+al*wh+ah*wl).
// mode: 0 = store fp32 C, 1 = C +=, 2 = store hi/lo planes Chp/Clp,
//       3 = QKV: cols<1024 -> hi/lo planes; cols>=1024 -> V transposed into Vh/Vl
//           at [(g*512)+(col-1024)][row&127] (g = row>>7).
// ysplit/wrowoff1: row-block >= ysplit switches W row offset + bias to (b1,bo1).
__global__ __launch_bounds__(256) void gemm_hl(
    const u16* __restrict__ Ahp, const u16* __restrict__ Alp, int lda,
    const u16* __restrict__ Whp, const u16* __restrict__ Wlp, int ldw,
    const void* __restrict__ b0, const void* __restrict__ b1, const void* __restrict__ b2,
    size_t bo0, size_t bo1, size_t bo2, int bshift,
    float* __restrict__ C, u16* __restrict__ Chp, u16* __restrict__ Clp,
    u16* __restrict__ Vh, u16* __restrict__ Vl, int ldc,
    int K, int act, int mode, int ysplit, size_t wrowoff1,
    const int* __restrict__ dflag) {
  const int isbf = *dflag;
  __shared__ __align__(16) u16 sAh[64][72];  // stride 144B (4 mod 32 banks) -> 2-way only
  __shared__ __align__(16) u16 sAl[64][72];
  __shared__ __align__(16) u16 sBh[64][72];
  __shared__ __align__(16) u16 sBl[64][72];

  int tid = threadIdx.x;
  int by = blockIdx.y;
  int row0 = by * 64, col0 = blockIdx.x * 64;
  int rsplit = (by >= ysplit);
  size_t wrow0 = (size_t)col0 + (rsplit ? wrowoff1 : 0);

  int wid = tid >> 6, lane = tid & 63, quad = lane >> 4, lm = lane & 15;
  int mrow = (wid & 1) * 32, ncol = (wid >> 1) * 32;

  f32x4 acc[2][2] = {};

  int sr = tid >> 2, sc = (tid & 3) * 16;

  for (int k0 = 0; k0 < K; k0 += 64) {
    const u16* p;
    p = Ahp + (size_t)(row0 + sr) * lda + k0 + sc;
    uint4 a0 = *(const uint4*)p, a1 = *(const uint4*)(p + 8);
    p = Alp + (size_t)(row0 + sr) * lda + k0 + sc;
    uint4 a2 = *(const uint4*)p, a3 = *(const uint4*)(p + 8);
    p = Whp + (wrow0 + sr) * (size_t)ldw + k0 + sc;
    uint4 w0 = *(const uint4*)p, w1 = *(const uint4*)(p + 8);
    p = Wlp + (wrow0 + sr) * (size_t)ldw + k0 + sc;
    uint4 w2 = *(const uint4*)p, w3 = *(const uint4*)(p + 8);
    __syncthreads();
    *(uint4*)&sAh[sr][sc] = a0; *(uint4*)&sAh[sr][sc + 8] = a1;
    *(uint4*)&sAl[sr][sc] = a2; *(uint4*)&sAl[sr][sc + 8] = a3;
    *(uint4*)&sBh[sr][sc] = w0; *(uint4*)&sBh[sr][sc + 8] = w1;
    *(uint4*)&sBl[sr][sc] = w2; *(uint4*)&sBl[sr][sc + 8] = w3;
    __syncthreads();
#pragma unroll
    for (int ks = 0; ks < 2; ++ks) {
      bf16x8 ah[2], al[2], wh[2], wl[2];
#pragma unroll
      for (int mi = 0; mi < 2; ++mi) {
        ah[mi] = *(const bf16x8*)&sAh[mrow + mi * 16 + lm][ks * 32 + quad * 8];
        al[mi] = *(const bf16x8*)&sAl[mrow + mi * 16 + lm][ks * 32 + quad * 8];
      }
#pragma unroll
      for (int ni = 0; ni < 2; ++ni) {
        wh[ni] = *(const bf16x8*)&sBh[ncol + ni * 16 + lm][ks * 32 + quad * 8];
        wl[ni] = *(const bf16x8*)&sBl[ncol + ni * 16 + lm][ks * 32 + quad * 8];
      }
#pragma unroll
      for (int mi = 0; mi < 2; ++mi)
#pragma unroll
        for (int ni = 0; ni < 2; ++ni) {
          acc[mi][ni] = __builtin_amdgcn_mfma_f32_16x16x32_bf16(ah[mi], wh[ni], acc[mi][ni], 0, 0, 0);
          acc[mi][ni] = __builtin_amdgcn_mfma_f32_16x16x32_bf16(al[mi], wh[ni], acc[mi][ni], 0, 0, 0);
          acc[mi][ni] = __builtin_amdgcn_mfma_f32_16x16x32_bf16(ah[mi], wl[ni], acc[mi][ni], 0, 0, 0);
        }
    }
  }
  // C/D layout: col=lane&15, row=quad*4+reg (m89-verified)
#pragma unroll
  for (int mi = 0; mi < 2; ++mi) {
#pragma unroll
    for (int ni = 0; ni < 2; ++ni) {
      int colg = col0 + ncol + ni * 16 + lm;
      const void* bp; size_t bo;
      if (rsplit) { bp = b1; bo = bo1 + colg; }
      else {
        int seg = colg >> bshift;
        bp = (seg == 0) ? b0 : ((seg == 1) ? b1 : b2);
        bo = (seg == 0) ? bo0 : ((seg == 1) ? bo1 : bo2);
        bo += (size_t)colg - ((size_t)seg << bshift);
      }
      float bv = ldin(bp, bo, isbf);
#pragma unroll
      for (int r = 0; r < 4; ++r) {
        int rowg = row0 + mrow + mi * 16 + quad * 4 + r;
        float v = acc[mi][ni][r] + bv;
        if (act) v = v * 0.5f * (1.f + erff(v * 0.70710678118654752f));
        if (mode == 3 && colg >= 1024) {
          int gg = rowg >> 7;
          size_t o = ((size_t)(gg * 512) + (colg - 1024)) * 128 + (rowg & 127);
          u16 hh = f2bf(v); Vh[o] = hh; Vl[o] = f2bf(v - bfu(hh));
        } else {
          size_t o = (size_t)rowg * ldc + colg;
          if (mode == 0) C[o] = v;
          else if (mode == 1) C[o] += v;
          else { u16 hh = f2bf(v); Chp[o] = hh; Clp[o] = f2bf(v - bfu(hh)); }
        }
      }
    }
  }
}

// MFMA attention: grid 128 = (g 8, h 4, tq 4), 256 threads (4 waves).
// Q,K from qkv hi/lo planes [1024][1536]; V from Vt planes [4096][128].
// Output O hi/lo planes [1024][512]. Same fragment scheme as gemm_hl (HW-validated).
__global__ __launch_bounds__(256) void attn_mfma(
    const u16* __restrict__ Qh, const u16* __restrict__ Ql,
    const u16* __restrict__ Vth, const u16* __restrict__ Vtl,
    u16* __restrict__ Oh, u16* __restrict__ Ol) {
  int tq = blockIdx.x & 3;
  int h = (blockIdx.x >> 2) & 3;
  int g = blockIdx.x >> 4;
  int tid = threadIdx.x;
  int w = tid >> 6, lane = tid & 63, quad = lane >> 4, lm = lane & 15;
  __shared__ float S[32][132];  // pad 4 mod 32 -> 2-way bank alias only (free)

  // Phase 1: S = (Q K^T) * 1/sqrt(dk). m=t (32 rows tq*32..), n=s (wave w: 32w..), k=d.
  f32x4 sacc[2][2] = {};
#pragma unroll
  for (int ks = 0; ks < 4; ++ks) {
    bf16x8 qh[2], ql[2];
#pragma unroll
    for (int mi = 0; mi < 2; ++mi) {
      size_t qi = (size_t)(g * 128 + tq * 32 + mi * 16 + lm) * 1536 + h * 128 + ks * 32 + quad * 8;
      qh[mi] = *(const bf16x8*)(Qh + qi);
      ql[mi] = *(const bf16x8*)(Ql + qi);
    }
#pragma unroll
    for (int ni = 0; ni < 2; ++ni) {
      size_t kix = (size_t)(g * 128 + w * 32 + ni * 16 + lm) * 1536 + 512 + h * 128 + ks * 32 + quad * 8;
      bf16x8 kh = *(const bf16x8*)(Qh + kix);
      bf16x8 kl = *(const bf16x8*)(Ql + kix);
#pragma unroll
      for (int mi = 0; mi < 2; ++mi) {
        sacc[mi][ni] = __builtin_amdgcn_mfma_f32_16x16x32_bf16(qh[mi], kh, sacc[mi][ni], 0, 0, 0);
        sacc[mi][ni] = __builtin_amdgcn_mfma_f32_16x16x32_bf16(ql[mi], kh, sacc[mi][ni], 0, 0, 0);
        sacc[mi][ni] = __builtin_amdgcn_mfma_f32_16x16x32_bf16(qh[mi], kl, sacc[mi][ni], 0, 0, 0);
      }
    }
  }
  const float scale = 0.08838834764831845f;
#pragma unroll
  for (int mi = 0; mi < 2; ++mi)
#pragma unroll
    for (int ni = 0; ni < 2; ++ni)
#pragma unroll
      for (int r = 0; r < 4; ++r)
        S[mi * 16 + quad * 4 + r][w * 32 + ni * 16 + lm] = sacc[mi][ni][r] * scale;
  __syncthreads();

  // Phase 2: softmax rows; 8 threads per row (consecutive lanes -> shfl_xor ok).
  {
    int row = tid >> 3, j = tid & 7;
    float* sp = &S[row][j * 16];
    float v[16];
    *(float4*)(v) = *(float4*)(sp);
    *(float4*)(v + 4) = *(float4*)(sp + 4);
    *(float4*)(v + 8) = *(float4*)(sp + 8);
    *(float4*)(v + 12) = *(float4*)(sp + 12);
    float mx = v[0];
#pragma unroll
    for (int i = 1; i < 16; ++i) mx = fmaxf(mx, v[i]);
    mx = fmaxf(mx, __shfl_xor(mx, 1));
    mx = fmaxf(mx, __shfl_xor(mx, 2));
    mx = fmaxf(mx, __shfl_xor(mx, 4));
    float sum = 0.f;
#pragma unroll
    for (int i = 0; i < 16; ++i) { v[i] = expf(v[i] - mx); sum += v[i]; }
    sum += __shfl_xor(sum, 1);
    sum += __shfl_xor(sum, 2);
    sum += __shfl_xor(sum, 4);
    float inv = 1.f / sum;
#pragma unroll
    for (int i = 0; i < 16; ++i) v[i] *= inv;
    *(float4*)(sp) = *(float4*)(v);
    *(float4*)(sp + 4) = *(float4*)(v + 4);
    *(float4*)(sp + 8) = *(float4*)(v + 8);
    *(float4*)(sp + 12) = *(float4*)(v + 12);
  }
  __syncthreads();

  // Phase 3: O = P V. m=t, n=d (wave w: 32w..), k=s. P from LDS (hi/lo split on the fly).
  f32x4 oacc[2][2] = {};
#pragma unroll
  for (int ks = 0; ks < 4; ++ks) {
    bf16x8 ph[2], pl[2];
#pragma unroll
    for (int mi = 0; mi < 2; ++mi) {
      float pv[8];
      const float* srow = &S[mi * 16 + lm][ks * 32 + quad * 8];
      *(float4*)(pv) = *(const float4*)srow;
      *(float4*)(pv + 4) = *(const float4*)(srow + 4);
      bf16x8 hh, ll;
#pragma unroll
      for (int i = 0; i < 8; ++i) {
        u16 hb = f2bf(pv[i]);
        hh[i] = (short)hb;
        ll[i] = (short)f2bf(pv[i] - bfu(hb));
      }
      ph[mi] = hh; pl[mi] = ll;
    }
#pragma unroll
    for (int ni = 0; ni < 2; ++ni) {
      size_t vi = (size_t)(g * 512 + h * 128 + w * 32 + ni * 16 + lm) * 128 + ks * 32 + quad * 8;
      bf16x8 vh = *(const bf16x8*)(Vth + vi);
      bf16x8 vl = *(const bf16x8*)(Vtl + vi);
#pragma unroll
      for (int mi = 0; mi < 2; ++mi) {
        oacc[mi][ni] = __builtin_amdgcn_mfma_f32_16x16x32_bf16(ph[mi], vh, oacc[mi][ni], 0, 0, 0);
        oacc[mi][ni] = __builtin_amdgcn_mfma_f32_16x16x32_bf16(pl[mi], vh, oacc[mi][ni], 0, 0, 0);
        oacc[mi][ni] = __builtin_amdgcn_mfma_f32_16x16x32_bf16(ph[mi], vl, oacc[mi][ni], 0, 0, 0);
      }
    }
  }
#pragma unroll
  for (int mi = 0; mi < 2; ++mi)
#pragma unroll
    for (int ni = 0; ni < 2; ++ni)
#pragma unroll
      for (int r = 0; r < 4; ++r) {
        int t = tq * 32 + mi * 16 + quad * 4 + r;
        int d = w * 32 + ni * 16 + lm;
        size_t o = (size_t)(g * 128 + t) * 512 + h * 128 + d;
        float val = oacc[mi][ni][r];
        u16 hb = f2bf(val);
        Oh[o] = hb;
        Ol[o] = f2bf(val - bfu(hb));
      }
}

// emb+pos LN, both encoders (1024 rows): writes fp32 x AND hi/lo planes.
__global__ __launch_bounds__(256) void emb_ln2(
    const void* __restrict__ qe, const void* __restrict__ ae, const void* __restrict__ pos,
    const void* __restrict__ w, const void* __restrict__ b,
    float* __restrict__ x, u16* __restrict__ oh, u16* __restrict__ ol,
    const int* __restrict__ dflag) {
  const int isbf = *dflag;
  const int D = 512;
  int row = blockIdx.x;
  const void* emb = (row < 512) ? qe : ae;
  int lr = row & 511, t = row & 127;
  __shared__ float sbuf[8];
  int i0 = threadIdx.x, i1 = threadIdx.x + 256;
  float v0 = ldin(emb, (size_t)lr * D + i0, isbf) + ldin(pos, (size_t)t * D + i0, isbf);
  float v1 = ldin(emb, (size_t)lr * D + i1, isbf) + ldin(pos, (size_t)t * D + i1, isbf);
  float mean = block_sum(v0 + v1, sbuf) / 512.f;
  float d0 = v0 - mean, d1 = v1 - mean;
  float var = block_sum(d0 * d0 + d1 * d1, sbuf) / 512.f;
  float inv = 1.0f / sqrtf(var + 1e-12f);
  float r0 = ldin(w, i0, isbf) * d0 * inv + ldin(b, i0, isbf);
  float r1 = ldin(w, i1, isbf) * d1 * inv + ldin(b, i1, isbf);
  size_t o0 = (size_t)row * D + i0, o1 = (size_t)row * D + i1;
  x[o0] = r0; x[o1] = r1;
  u16 h0 = f2bf(r0); oh[o0] = h0; ol[o0] = f2bf(r0 - bfu(h0));
  u16 h1 = f2bf(r1); oh[o1] = h1; ol[o1] = f2bf(r1 - bfu(h1));
}

// LN fp32 in -> optional fp32 out (in-place safe) + hi/lo planes.
__global__ __launch_bounds__(256) void ln2(
    const float* __restrict__ in, float* __restrict__ outf,
    u16* __restrict__ oh, u16* __restrict__ ol,
    const void* __restrict__ w, const void* __restrict__ b, size_t wboff,
    const int* __restrict__ dflag) {
  const int isbf = *dflag;
  const int D = 512;
  int row = blockIdx.x;
  __shared__ float sbuf[8];
  int i0 = threadIdx.x, i1 = threadIdx.x + 256;
  float v0 = in[(size_t)row * D + i0];
  float v1 = in[(size_t)row * D + i1];
  float mean = block_sum(v0 + v1, sbuf) / 512.f;
  float d0 = v0 - mean, d1 = v1 - mean;
  float var = block_sum(d0 * d0 + d1 * d1, sbuf) / 512.f;
  float inv = 1.0f / sqrtf(var + 1e-12f);
  float r0 = ldin(w, wboff + i0, isbf) * d0 * inv + ldin(b, wboff + i0, isbf);
  float r1 = ldin(w, wboff + i1, isbf) * d1 * inv + ldin(b, wboff + i1, isbf);
  size_t o0 = (size_t)row * D + i0, o1 = (size_t)row * D + i1;
  if (outf) { outf[o0] = r0; outf[o1] = r1; }
  u16 h0 = f2bf(r0); oh[o0] = h0; ol[o0] = f2bf(r0 - bfu(h0));
  u16 h1 = f2bf(r1); oh[o1] = h1; ol[o1] = f2bf(r1 - bfu(h1));
}

// ===========================================================================
// head kernels (shared) + fallback round-6 kernels
// ===========================================================================

__global__ __launch_bounds__(64) void proj_ce_kernel(const float* __restrict__ q,
                                                     const void* __restrict__ ce,
                                                     float* __restrict__ out, int D, int NC,
                                                     const int* __restrict__ dflag) {
  const int isbf = *dflag;
  int row = blockIdx.x;
  for (int c = 0; c < NC; ++c) {
    float acc = 0.f;
    for (int d = threadIdx.x; d < D; d += 64)
      acc = fmaf(q[(size_t)row * D + d], ldin(ce, (size_t)c * D + d, isbf), acc);
    acc = wave_sum(acc);
    if (threadIdx.x == 0) out[row * NC + c] = acc;
  }
}

__global__ __launch_bounds__(64) void gram_kernel(const void* __restrict__ ce,
                                                  float* __restrict__ G, int D, int NC,
                                                  const int* __restrict__ dflag) {
  const int isbf = *dflag;
  int c = blockIdx.x / NC, c2 = blockIdx.x % NC;
  float acc = 0.f;
  for (int d = threadIdx.x; d < D; d += 64)
    acc = fmaf(ldin(ce, (size_t)c * D + d, isbf), ldin(ce, (size_t)c2 * D + d, isbf), acc);
  acc = wave_sum(acc);
  if (threadIdx.x == 0) G[blockIdx.x] = acc;
}

__global__ __launch_bounds__(128) void sim_scores_kernel(
    const float* __restrict__ q, const float* __restrict__ k, const void* __restrict__ qa,
    const void* __restrict__ aq, const float* __restrict__ qc, const float* __restrict__ kc,
    const float* __restrict__ G, float* __restrict__ p_out, float* __restrict__ pa_out,
    int B, int T1, int T2, int D, int NC, const int* __restrict__ dflag) {
  const int isbf = *dflag;
  int t = blockIdx.x % T1;
  int b = blockIdx.x / T1;
  int s = threadIdx.x;
  __shared__ float qs[512];
  __shared__ float Gs[25];
  __shared__ float qcs[5];
  __shared__ float sbuf[8];
  for (int i = threadIdx.x; i < D; i += 128) qs[i] = q[(size_t)(b * T1 + t) * D + i];
  if (threadIdx.x < NC * NC) Gs[threadIdx.x] = G[threadIdx.x];
  if (threadIdx.x < NC) qcs[threadIdx.x] = qc[(b * T1 + t) * NC + threadIdx.x];
  __syncthreads();
  const float* krow = k + (size_t)(b * T2 + s) * D;
  float sc = 0.f;
#pragma unroll 8
  for (int d = 0; d < 512; ++d) sc = fmaf(qs[d], krow[d], sc);
  float qav[5], aqv[5];
#pragma unroll
  for (int c = 0; c < 5; ++c) {
    qav[c] = ldin(qa, (size_t)((b * T1 + t) * T2 + s) * NC + c, isbf);
    aqv[c] = ldin(aq, (size_t)((b * T2 + s) * T1 + t) * NC + c, isbf);
  }
#pragma unroll
  for (int c = 0; c < 5; ++c) {
    sc = fmaf(aqv[c], qcs[c], sc);
    sc = fmaf(qav[c], kc[(b * T2 + s) * NC + c], sc);
#pragma unroll
    for (int c2 = 0; c2 < 5; ++c2) sc = fmaf(qav[c] * Gs[c * 5 + c2], aqv[c2], sc);
  }
  float mx = block_max(sc, sbuf);
  float e = expf(sc - mx);
  float ssum = block_sum(e, sbuf);
  float p = e / ssum;
  float mx2 = block_max(p, sbuf);
  float e2 = expf(1000.f * (p - mx2));
  float s2 = block_sum(e2, sbuf);
  float pf = fminf(fmaxf(e2 / s2, 0.f), 1.f);
  p_out[(size_t)(b * T1 + t) * T2 + s] = pf;
#pragma unroll
  for (int c = 0; c < 5; ++c) {
    float pc = block_sum(pf * aqv[c], sbuf);
    if (threadIdx.x == 0) pa_out[(b * T1 + t) * NC + c] = pc;
  }
}

__global__ __launch_bounds__(512) void sim_x_kernel(const float* __restrict__ p, const float* __restrict__ k,
                                                    const float* __restrict__ pa,
                                                    const void* __restrict__ ce,
                                                    float* __restrict__ x, int B, int T1, int T2, int D, int NC,
                                                    const int* __restrict__ dflag) {
  const int isbf = *dflag;
  int t = blockIdx.x % T1;
  int b = blockIdx.x / T1;
  int d = threadIdx.x;
  __shared__ float ps[128];
  __shared__ float pav[5];
  if (threadIdx.x < T2) ps[threadIdx.x] = p[(size_t)(b * T1 + t) * T2 + threadIdx.x];
  if (threadIdx.x < NC) pav[threadIdx.x] = pa[(b * T1 + t) * NC + threadIdx.x];
  __syncthreads();
  float acc = 0.f;
  for (int s = 0; s < 128; ++s) acc = fmaf(ps[s], k[(size_t)(b * T2 + s) * D + d], acc);
#pragma unroll
  for (int c = 0; c < 5; ++c) acc = fmaf(pav[c], ldin(ce, (size_t)c * D + d, isbf), acc);
  x[(size_t)(b * T1 + t) * D + d] = acc;
}

__global__ __launch_bounds__(512) void mean_kernel(const float* __restrict__ x, float* __restrict__ xm,
                                                   int T, int D) {
  int b = blockIdx.x;
  int d = threadIdx.x;
  float acc = 0.f;
  for (int t = 0; t < T; ++t) acc += x[(size_t)(b * T + t) * D + d];
  xm[(size_t)b * D + d] = acc / (float)T;
}

__global__ __launch_bounds__(64) void cls_kernel(const float* __restrict__ xm,
                                                 const void* __restrict__ w,
                                                 const void* __restrict__ bias,
                                                 void* __restrict__ out, int D, int NO,
                                                 const int* __restrict__ dflag) {
  const int isbf = *dflag;
  int j = blockIdx.x % NO;
  int b = blockIdx.x / NO;
  float acc = 0.f;
  for (int d = threadIdx.x; d < D; d += 64)
    acc = fmaf(xm[(size_t)b * D + d], ldin(w, (size_t)d * NO + j, isbf), acc);
  acc = wave_sum(acc);
  if (threadIdx.x == 0) {
    float val = acc + ldin(bias, j, isbf);
    if (isbf) ((__hip_bfloat16*)out)[b * NO + j] = __float2bfloat16(val);
    else ((float*)out)[b * NO + j] = val;
  }
}

// ---- round-6 fallback kernels (used only if ws too small for fast path) ----

__global__ __launch_bounds__(256) void gemm_mfma(
    const float* __restrict__ A, const void* __restrict__ W, size_t woff,
    const void* __restrict__ bias, size_t boff,
    float* __restrict__ C, int M, int N, int K, int act, int addto,
    const int* __restrict__ dflag) {
  const int isbf = *dflag;
  __shared__ __align__(16) u16 Ah[64][40];
  __shared__ __align__(16) u16 Al[64][40];
  __shared__ __align__(16) u16 Wh[64][40];
  __shared__ __align__(16) u16 Wl[64][40];
  int tid = threadIdx.x;
  int row0 = blockIdx.y * 64, col0 = blockIdx.x * 64;
  int wid = tid >> 6, lane = tid & 63;
  int quad = lane >> 4, lm = lane & 15;
  int mrow = (wid & 1) * 32, ncol = (wid >> 1) * 32;
  f32x4 acc[2][2] = {};
  int ar = tid >> 2, akc = (tid & 3) * 8;
  int bk = tid >> 3, bn0 = (tid & 7) * 8;
  for (int k0 = 0; k0 < K; k0 += 32) {
    const float* ap = A + (size_t)(row0 + ar) * K + k0 + akc;
    float av[8];
    *(float4*)(av) = *(const float4*)ap;
    *(float4*)(av + 4) = *(const float4*)(ap + 4);
    unsigned hp[4], lp[4];
#pragma unroll
    for (int j = 0; j < 4; ++j) {
      u16 h0 = f2bf(av[2 * j]);
      u16 h1 = f2bf(av[2 * j + 1]);
      u16 l0 = f2bf(av[2 * j] - bfu(h0));
      u16 l1 = f2bf(av[2 * j + 1] - bfu(h1));
      hp[j] = (unsigned)h0 | ((unsigned)h1 << 16);
      lp[j] = (unsigned)l0 | ((unsigned)l1 << 16);
    }
    *(uint4*)&Ah[ar][akc] = make_uint4(hp[0], hp[1], hp[2], hp[3]);
    *(uint4*)&Al[ar][akc] = make_uint4(lp[0], lp[1], lp[2], lp[3]);
    float wv[8];
    size_t welem = woff + (size_t)(k0 + bk) * N + col0 + bn0;
    if (isbf) {
      const u16* wp = (const u16*)W + welem;
      uint4 raw = *(const uint4*)wp;
      wv[0] = bfu((u16)(raw.x & 0xFFFF)); wv[1] = bfu((u16)(raw.x >> 16));
      wv[2] = bfu((u16)(raw.y & 0xFFFF)); wv[3] = bfu((u16)(raw.y >> 16));
      wv[4] = bfu((u16)(raw.z & 0xFFFF)); wv[5] = bfu((u16)(raw.z >> 16));
      wv[6] = bfu((u16)(raw.w & 0xFFFF)); wv[7] = bfu((u16)(raw.w >> 16));
    } else {
      const float* wp = (const float*)W + welem;
      *(float4*)(wv) = *(const float4*)wp;
      *(float4*)(wv + 4) = *(const float4*)(wp + 4);
    }
#pragma unroll
    for (int i = 0; i < 8; ++i) {
      u16 h = f2bf(wv[i]);
      u16 l = f2bf(wv[i] - bfu(h));
      Wh[bn0 + i][bk] = h;
      Wl[bn0 + i][bk] = l;
    }
    __syncthreads();
#pragma unroll
    for (int mi = 0; mi < 2; ++mi) {
      bf16x8 ah = *(const bf16x8*)&Ah[mrow + mi * 16 + lm][quad * 8];
      bf16x8 al = *(const bf16x8*)&Al[mrow + mi * 16 + lm][quad * 8];
#pragma unroll
      for (int ni = 0; ni < 2; ++ni) {
        bf16x8 wh = *(const bf16x8*)&Wh[ncol + ni * 16 + lm][quad * 8];
        bf16x8 wl = *(const bf16x8*)&Wl[ncol + ni * 16 + lm][quad * 8];
        acc[mi][ni] = __builtin_amdgcn_mfma_f32_16x16x32_bf16(ah, wh, acc[mi][ni], 0, 0, 0);
        acc[mi][ni] = __builtin_amdgcn_mfma_f32_16x16x32_bf16(al, wh, acc[mi][ni], 0, 0, 0);
        acc[mi][ni] = __builtin_amdgcn_mfma_f32_16x16x32_bf16(ah, wl, acc[mi][ni], 0, 0, 0);
      }
    }
    __syncthreads();
  }
#pragma unroll
  for (int mi = 0; mi < 2; ++mi) {
#pragma unroll
    for (int ni = 0; ni < 2; ++ni) {
      int colg = col0 + ncol + ni * 16 + lm;
      float bv = ldin(bias, boff + colg, isbf);
#pragma unroll
      for (int r = 0; r < 4; ++r) {
        int rowg = row0 + mrow + mi * 16 + quad * 4 + r;
        float v = acc[mi][ni][r] + bv;
        if (act) v = v * 0.5f * (1.f + erff(v * 0.70710678118654752f));
        size_t o = (size_t)rowg * N + colg;
        if (addto) C[o] += v; else C[o] = v;
      }
    }
  }
}

__global__ __launch_bounds__(256) void emb_ln_kernel(const void* __restrict__ emb,
                                                     const void* __restrict__ pos,
                                                     const void* __restrict__ w,
                                                     const void* __restrict__ b,
                                                     float* __restrict__ out, int T, int D,
                                                     const int* __restrict__ dflag) {
  const int isbf = *dflag;
  int row = blockIdx.x;
  int t = row % T;
  __shared__ float sbuf[8];
  int i0 = threadIdx.x, i1 = threadIdx.x + 256;
  float v0 = ldin(emb, (size_t)row * D + i0, isbf) + ldin(pos, (size_t)t * D + i0, isbf);
  float v1 = ldin(emb, (size_t)row * D + i1, isbf) + ldin(pos, (size_t)t * D + i1, isbf);
  float mean = block_sum(v0 + v1, sbuf) / (float)D;
  float d0 = v0 - mean, d1 = v1 - mean;
  float var = block_sum(d0 * d0 + d1 * d1, sbuf) / (float)D;
  float inv = 1.0f / sqrtf(var + 1e-12f);
  out[(size_t)row * D + i0] = ldin(w, i0, isbf) * d0 * inv + ldin(b, i0, isbf);
  out[(size_t)row * D + i1] = ldin(w, i1, isbf) * d1 * inv + ldin(b, i1, isbf);
}

__global__ __launch_bounds__(256) void ln_kernel(const float* __restrict__ in, float* __restrict__ out,
                                                 const void* __restrict__ w, const void* __restrict__ b,
                                                 size_t wboff, int D, const int* __restrict__ dflag) {
  const int isbf = *dflag;
  int row = blockIdx.x;
  __shared__ float sbuf[8];
  int i0 = threadIdx.x, i1 = threadIdx.x + 256;
  float v0 = in[(size_t)row * D + i0];
  float v1 = in[(size_t)row * D + i1];
  float mean = block_sum(v0 + v1, sbuf) / (float)D;
  float d0 = v0 - mean, d1 = v1 - mean;
  float var = block_sum(d0 * d0 + d1 * d1, sbuf) / (float)D;
  float inv = 1.0f / sqrtf(var + 1e-12f);
  out[(size_t)row * D + i0] = ldin(w, wboff + i0, isbf) * d0 * inv + ldin(b, wboff + i0, isbf);
  out[(size_t)row * D + i1] = ldin(w, wboff + i1, isbf) * d1 * inv + ldin(b, wboff + i1, isbf);
}

__global__ __launch_bounds__(128) void attn_kernel(const float* __restrict__ q, const float* __restrict__ k,
                                                   const float* __restrict__ v, float* __restrict__ o,
                                                   int B, int H, int T, int dk) {
  int t = blockIdx.x % T;
  int h = (blockIdx.x / T) % H;
  int b = blockIdx.x / (T * H);
  int D = H * dk;
  int tid = threadIdx.x;
  __shared__ float qs[128];
  __shared__ float ps[128];
  __shared__ float sbuf[8];
  qs[tid] = q[(size_t)(b * T + t) * D + h * dk + tid];
  __syncthreads();
  const float* krow = k + (size_t)(b * T + tid) * D + h * dk;
  float sc = 0.f;
#pragma unroll 8
  for (int d = 0; d < 128; ++d) sc = fmaf(qs[d], krow[d], sc);
  sc *= 0.08838834764831845f;
  float mx = block_max(sc, sbuf);
  float e = expf(sc - mx);
  float s = block_sum(e, sbuf);
  ps[tid] = e / s;
  __syncthreads();
  float acc = 0.f;
  for (int s2 = 0; s2 < 128; ++s2)
    acc = fmaf(ps[s2], v[(size_t)(b * T + s2) * D + h * dk + tid], acc);
  o[(size_t)(b * T + t) * D + h * dk + tid] = acc;
}

// ===========================================================================
extern "C" void kernel_launch(void* const* d_in, const int* in_sizes, int n_in,
                              void* d_out, int out_size, void* d_ws, size_t ws_size,
                              hipStream_t stream) {
  const int B = 4, T = 128, D = 512, H = 4, NL = 4, DFF = 2048, NC = 5;
  const void *q_emb = d_in[0], *a_emb = d_in[1], *qa = d_in[2], *aqr = d_in[3],
             *ce = d_in[4], *pos = d_in[5], *pe_w = d_in[6], *pe_b = d_in[7],
             *Wq = d_in[8], *bq = d_in[9], *Wk = d_in[10], *bk = d_in[11],
             *Wv = d_in[12], *bv = d_in[13], *Wo = d_in[14], *bo = d_in[15],
             *ff1w = d_in[16], *ff1b = d_in[17], *ff2w = d_in[18], *ff2b = d_in[19],
             *lnin_w = d_in[20], *lnin_b = d_in[21], *lnout_w = d_in[22], *lnout_b = d_in[23],
             *simWq = d_in[24], *simbq = d_in[25], *simWk = d_in[26], *simbk = d_in[27],
             *clsw = d_in[28], *clsb = d_in[29];

  const size_t REQ = 23100000ull;
  if (ws_size >= REQ) {
    // -------- FAST PATH --------
    char* base = (char*)d_ws;
    float* x = (float*)(base + 0);                 // [1024][512] fp32
    u16* xch = (u16*)(base + 2097152);             // [1024][512] hi
    u16* xcl = (u16*)(base + 3145728);             // lo
    u16* qkvh = (u16*)(base + 4194304);            // [1024][1536] hi (3 MB)
    u16* qkvl = (u16*)(base + 7340032);            // lo (3 MB)
    u16* ffch = (u16*)(base + 10485760);           // [1024][2048] hi (4 MB)
    u16* ffcl = (u16*)(base + 14680064);           // lo (4 MB)
    u16* Vth = (u16*)(base + 10485760);            // [4096][128] hi (1 MB) — overlays ffch (dead in attn phase)
    u16* Vtl = (u16*)(base + 11534336);            // lo (1 MB)
    u16* wth = (u16*)(base + 18874368);            // weight hi plane (2 MB = [2048][512])
    u16* wtl = (u16*)(base + 20971520);            // weight lo plane (2 MB)
    int* dflag = (int*)(base + 23068672);
    // sim overlays inside qkv region (dead then)
    float* qkb = (float*)(base + 4194304);         // [1024][512] fp32
    float* pbuf = (float*)(base + 6291456);
    float* pabuf = (float*)(base + 6553600);
    float* qcbuf = (float*)(base + 6563840);
    float* kcbuf = (float*)(base + 6574080);
    float* Gbuf = (float*)(base + 6584320);
    float* xmean = (float*)(base + 6584448);
    float* xsim = (float*)(base + 6592640);

    flag_kernel<<<1, 64, 0, stream>>>(pe_w, dflag);
    emb_ln2<<<1024, 256, 0, stream>>>(q_emb, a_emb, pos, pe_w, pe_b, x, xch, xcl, dflag);

    for (int l = 0; l < NL; ++l) {
      size_t wDD = (size_t)l * D * D, bD = (size_t)l * D;
      // QKV+O weights in one convT: wt rows 0..1535 = Q|K|V, 1536..2047 = O
      convT<<<dim3(16, 16, 4), 256, 0, stream>>>(Wq, Wk, Wv, Wo, wDD, 512, 512, wth, wtl, dflag);
      // QKV gemm, mode 3: Q/K -> qkv planes, V -> Vt planes (transposed)
      gemm_hl<<<dim3(24, 16), 256, 0, stream>>>(xch, xcl, 512, wth, wtl, 512,
                                                bq, bk, bv, bD, bD, bD, 9,
                                                nullptr, qkvh, qkvl, Vth, Vtl, 1536,
                                                512, 0, 3, 9999, 0, dflag);
      attn_mfma<<<128, 256, 0, stream>>>(qkvh, qkvl, Vth, Vtl, xch, xcl);
      // O-proj (weights at wt rows 1536..)
      gemm_hl<<<dim3(8, 16), 256, 0, stream>>>(xch, xcl, 512, wth + (size_t)1536 * 512,
                                               wtl + (size_t)1536 * 512, 512,
                                               bo, bo, bo, bD, bD, bD, 9,
                                               x, nullptr, nullptr, nullptr, nullptr, 512,
                                               512, 0, 1, 9999, 0, dflag);
      ln2<<<1024, 256, 0, stream>>>(x, nullptr, xch, xcl, lnin_w, lnin_b, bD, dflag);
      // FF1
      convT<<<dim3(64, 16, 1), 256, 0, stream>>>(ff1w, ff1w, ff1w, ff1w, (size_t)l * D * DFF,
                                                 512, 2048, wth, wtl, dflag);
      gemm_hl<<<dim3(32, 16), 256, 0, stream>>>(xch, xcl, 512, wth, wtl, 512,
                                                ff1b, ff1b, ff1b,
                                                (size_t)l * DFF, (size_t)l * DFF, (size_t)l * DFF, 11,
                                                nullptr, ffch, ffcl, nullptr, nullptr, 2048,
                                                512, 1, 2, 9999, 0, dflag);
      // FF2
      convT<<<dim3(16, 64, 1), 256, 0, stream>>>(ff2w, ff2w, ff2w, ff2w, (size_t)l * DFF * D,
                                                 2048, 512, wth, wtl, dflag);
      gemm_hl<<<dim3(8, 16), 256, 0, stream>>>(ffch, ffcl, 2048, wth, wtl, 2048,
                                               ff2b, ff2b, ff2b, bD, bD, bD, 9,
                                               x, nullptr, nullptr, nullptr, nullptr, 512,
                                               2048, 0, 1, 9999, 0, dflag);
      ln2<<<1024, 256, 0, stream>>>(x, x, xch, xcl, lnout_w, lnout_b, bD, dflag);
    }

    // Sim head: fused GEMM (rows 0-511 q-enc * simWq; 512-1023 a-enc * simWk)
    convT<<<dim3(16, 16, 2), 256, 0, stream>>>(simWq, simWk, simWk, simWk, 0, 512, 512, wth, wtl, dflag);
    gemm_hl<<<dim3(8, 16), 256, 0, stream>>>(xch, xcl, 512, wth, wtl, 512,
                                             simbq, simbk, simbk, 0, 0, 0, 9,
                                             qkb, nullptr, nullptr, nullptr, nullptr, 512,
                                             512, 0, 0, 8, 512, dflag);
    float* qb = qkb;
    float* kb = qkb + (size_t)512 * 512;
    proj_ce_kernel<<<512, 64, 0, stream>>>(qb, ce, qcbuf, D, NC, dflag);
    proj_ce_kernel<<<512, 64, 0, stream>>>(kb, ce, kcbuf, D, NC, dflag);
    gram_kernel<<<25, 64, 0, stream>>>(ce, Gbuf, D, NC, dflag);
    sim_scores_kernel<<<512, 128, 0, stream>>>(qb, kb, qa, aqr, qcbuf, kcbuf, Gbuf, pbuf, pabuf,
                                               B, T, T, D, NC, dflag);
    sim_x_kernel<<<512, 512, 0, stream>>>(pbuf, kb, pabuf, ce, xsim, B, T, T, D, NC, dflag);
    mean_kernel<<<4, 512, 0, stream>>>(xsim, xmean, T, D);
    cls_kernel<<<12, 64, 0, stream>>>(xmean, clsw, clsb, d_out, D, 3, dflag);
    return;
  }

  // -------- FALLBACK: round-6 passing path --------
  float* ws = (float*)d_ws;
  const size_t S = (size_t)512 * 512;
  float* qe = ws;
  float* ae = ws + S;
  float* hb = ws + 2 * S;
  float* rb = ws + 3 * S;
  float* qb = rb;
  float* kb = rb + S;
  float* vb = rb + 2 * S;
  float* ob = rb + 3 * S;
  float* ffb = rb;
  float* pbuf = rb + 2 * S;
  float* pabuf = pbuf + 65536;
  float* qcbuf = pabuf + 2560;
  float* kcbuf = qcbuf + 2560;
  float* Gbuf = kcbuf + 2560;
  float* xmean = Gbuf + 32;
  float* xsim = rb + 3 * S;
  int* dflag = (int*)(ws + 7 * S);

  const int M = B * T;
  dim3 gD(8, 8), gF1(32, 8), gF2(8, 8);

  flag_kernel<<<1, 64, 0, stream>>>(pe_w, dflag);
  for (int e = 0; e < 2; ++e) {
    float* x = (e == 0) ? qe : ae;
    const void* emb = (e == 0) ? q_emb : a_emb;
    emb_ln_kernel<<<M, 256, 0, stream>>>(emb, pos, pe_w, pe_b, x, T, D, dflag);
    for (int l = 0; l < NL; ++l) {
      size_t wDD = (size_t)l * D * D, bD = (size_t)l * D;
      gemm_mfma<<<gD, 256, 0, stream>>>(x, Wq, wDD, bq, bD, qb, M, D, D, 0, 0, dflag);
      gemm_mfma<<<gD, 256, 0, stream>>>(x, Wk, wDD, bk, bD, kb, M, D, D, 0, 0, dflag);
      gemm_mfma<<<gD, 256, 0, stream>>>(x, Wv, wDD, bv, bD, vb, M, D, D, 0, 0, dflag);
      attn_kernel<<<B * H * T, 128, 0, stream>>>(qb, kb, vb, ob, B, H, T, D / H);
      gemm_mfma<<<gD, 256, 0, stream>>>(ob, Wo, wDD, bo, bD, x, M, D, D, 0, 1, dflag);
      ln_kernel<<<M, 256, 0, stream>>>(x, hb, lnin_w, lnin_b, bD, D, dflag);
      gemm_mfma<<<gF1, 256, 0, stream>>>(hb, ff1w, (size_t)l * D * DFF, ff1b, (size_t)l * DFF,
                                         ffb, M, DFF, D, 1, 0, dflag);
      gemm_mfma<<<gF2, 256, 0, stream>>>(ffb, ff2w, (size_t)l * DFF * D, ff2b, bD,
                                         x, M, D, DFF, 0, 1, dflag);
      ln_kernel<<<M, 256, 0, stream>>>(x, x, lnout_w, lnout_b, bD, D, dflag);
    }
  }
  gemm_mfma<<<gD, 256, 0, stream>>>(qe, simWq, 0, simbq, 0, qb, M, D, D, 0, 0, dflag);
  gemm_mfma<<<gD, 256, 0, stream>>>(ae, simWk, 0, simbk, 0, kb, M, D, D, 0, 0, dflag);
  proj_ce_kernel<<<M, 64, 0, stream>>>(qb, ce, qcbuf, D, NC, dflag);
  proj_ce_kernel<<<M, 64, 0, stream>>>(kb, ce, kcbuf, D, NC, dflag);
  gram_kernel<<<NC * NC, 64, 0, stream>>>(ce, Gbuf, D, NC, dflag);
  sim_scores_kernel<<<B * T, 128, 0, stream>>>(qb, kb, qa, aqr, qcbuf, kcbuf, Gbuf, pbuf, pabuf,
                                               B, T, T, D, NC, dflag);
  sim_x_kernel<<<B * T, 512, 0, stream>>>(pbuf, kb, pabuf, ce, xsim, B, T, T, D, NC, dflag);
  mean_kernel<<<B, 512, 0, stream>>>(xsim, xmean, T, D);
  cls_kernel<<<B * 3, 64, 0, stream>>>(xmean, clsw, clsb, d_out, D, 3, dflag);
}

// Round 9
// 606.239 us; speedup vs baseline: 5.3647x; 1.2491x over previous
//
#include <hip/hip_runtime.h>
#include <hip/hip_bf16.h>
#include <math.h>

typedef unsigned short u16;
typedef __attribute__((ext_vector_type(8))) short bf16x8;   // 8 bf16 (4 VGPRs)
typedef __attribute__((ext_vector_type(4))) float f32x4;

// Inputs may be bf16 or fp32; device flag (pe_w all-ones: first u16 0x3F80 iff
// bf16, 0x0000 iff fp32 1.0f). r1-r6 evidence: inputs are fp32, but keep flag.
__device__ __forceinline__ float ldin(const void* p, size_t i, int isbf) {
  if (isbf) return __bfloat162float(((const __hip_bfloat16*)p)[i]);
  return ((const float*)p)[i];
}
__device__ __forceinline__ float bfu(u16 u) { return __builtin_bit_cast(float, (unsigned)u << 16); }
__device__ __forceinline__ u16 f2bf(float x) {  // round-to-nearest-even
  unsigned u = __builtin_bit_cast(unsigned, x);
  unsigned r = u + 0x7FFFu + ((u >> 16) & 1u);
  return (u16)(r >> 16);
}

__device__ __forceinline__ float wave_sum(float v) {
#pragma unroll
  for (int o = 32; o > 0; o >>= 1) v += __shfl_down(v, o);
  return v;
}

__device__ __forceinline__ float block_sum(float v, float* sbuf) {
  int lane = threadIdx.x & 63;
  int wid = threadIdx.x >> 6;
#pragma unroll
  for (int o = 32; o > 0; o >>= 1) v += __shfl_down(v, o);
  __syncthreads();
  if (lane == 0) sbuf[wid] = v;
  __syncthreads();
  int nw = blockDim.x >> 6;
  if (wid == 0) {
    float r = (lane < nw) ? sbuf[lane] : 0.f;
#pragma unroll
    for (int o = 4; o > 0; o >>= 1) r += __shfl_down(r, o);
    if (lane == 0) sbuf[0] = r;
  }
  __syncthreads();
  return sbuf[0];
}

__device__ __forceinline__ float block_max(float v, float* sbuf) {
  int lane = threadIdx.x & 63;
  int wid = threadIdx.x >> 6;
#pragma unroll
  for (int o = 32; o > 0; o >>= 1) v = fmaxf(v, __shfl_down(v, o));
  __syncthreads();
  if (lane == 0) sbuf[wid] = v;
  __syncthreads();
  int nw = blockDim.x >> 6;
  if (wid == 0) {
    float r = (lane < nw) ? sbuf[lane] : -INFINITY;
#pragma unroll
    for (int o = 4; o > 0; o >>= 1) r = fmaxf(r, __shfl_down(r, o));
    if (lane == 0) sbuf[0] = r;
  }
  __syncthreads();
  return sbuf[0];
}

__global__ void flag_kernel(const void* pe_w, int* flag) {
  if (threadIdx.x == 0 && blockIdx.x == 0)
    *flag = (((const unsigned short*)pe_w)[0] != 0) ? 1 : 0;
}

// init: dtype flag + zero the sim accumulators (ws is poisoned 0xAA each call)
__global__ void init_kernel(const void* pe_w, int* flag, float* Pbar, float* pabar) {
  int t = threadIdx.x;
  if (t == 0) *flag = (((const unsigned short*)pe_w)[0] != 0) ? 1 : 0;
  if (t < 512) Pbar[t] = 0.f;
  if (t < 20) pabar[t] = 0.f;
}

// ===========================================================================
// FAST PATH kernels
// ===========================================================================

// Generalized weight convert+transpose. z -> (t = z & tmask, l = z >> lshift).
// src = ptrs[t] + l*srcStride, [K][N] row-major (flag dtype).
// dst = Dh/Dl + l*layerStride + t*tensorStride, [N][K] row-major u16 planes.
__global__ __launch_bounds__(256) void convT2(
    const void* __restrict__ S0, const void* __restrict__ S1,
    const void* __restrict__ S2, const void* __restrict__ S3,
    size_t srcStride, int K, int N, u16* __restrict__ Dh, u16* __restrict__ Dl,
    size_t layerStride, size_t tensorStride, int tmask, int lshift,
    const int* __restrict__ dflag) {
  const int isbf = *dflag;
  int z = blockIdx.z;
  int t = z & tmask, l = z >> lshift;
  const void* S = (t == 0) ? S0 : ((t == 1) ? S1 : ((t == 2) ? S2 : S3));
  size_t soff = (size_t)l * srcStride;
  size_t doff = (size_t)l * layerStride + (size_t)t * tensorStride;
  int n0 = blockIdx.x * 32, k0 = blockIdx.y * 32;
  __shared__ float tt[32][33];
  int tx = threadIdx.x & 31, ty = threadIdx.x >> 5;
#pragma unroll
  for (int j = 0; j < 4; ++j) {
    int r = ty + j * 8;  // local k
    tt[r][tx] = ldin(S, soff + (size_t)(k0 + r) * N + n0 + tx, isbf);
  }
  __syncthreads();
#pragma unroll
  for (int j = 0; j < 4; ++j) {
    int r = ty + j * 8;  // local n
    float v = tt[tx][r];
    u16 h = f2bf(v);
    u16 lo = f2bf(v - bfu(h));
    size_t o = doff + (size_t)(n0 + r) * K + k0 + tx;
    Dh[o] = h;
    Dl[o] = lo;
  }
}

// MFMA GEMM on pre-split hi/lo planes.
// 64x64 tile, BK=64, 256 threads = 4 waves. 3 MFMAs/frag (ah*wh+al*wh+ah*wl).
// mode: 0 = store fp32 C, 1 = atomicAdd into C (supports split-K via gridDim.z),
//       2 = store hi/lo planes Chp/Clp,
//       3 = QKV: cols<1024 -> hi/lo planes; cols>=1024 -> V transposed into Vh/Vl.
// Split-K: gridDim.z partitions K; bias applied only by z==0 (mode 1 only).
__global__ __launch_bounds__(256) void gemm_hl(
    const u16* __restrict__ Ahp, const u16* __restrict__ Alp, int lda,
    const u16* __restrict__ Whp, const u16* __restrict__ Wlp, int ldw,
    const void* __restrict__ b0, const void* __restrict__ b1, const void* __restrict__ b2,
    size_t bo0, size_t bo1, size_t bo2, int bshift,
    float* __restrict__ C, u16* __restrict__ Chp, u16* __restrict__ Clp,
    u16* __restrict__ Vh, u16* __restrict__ Vl, int ldc,
    int K, int act, int mode, int ysplit, size_t wrowoff1,
    const int* __restrict__ dflag) {
  const int isbf = *dflag;
  __shared__ __align__(16) u16 sAh[64][72];  // stride 144B (4 mod 32 banks) -> 2-way only
  __shared__ __align__(16) u16 sAl[64][72];
  __shared__ __align__(16) u16 sBh[64][72];
  __shared__ __align__(16) u16 sBl[64][72];

  int tid = threadIdx.x;
  int by = blockIdx.y;
  int row0 = by * 64, col0 = blockIdx.x * 64;
  int rsplit = (by >= ysplit);
  size_t wrow0 = (size_t)col0 + (rsplit ? wrowoff1 : 0);
  int Ksub = K / (int)gridDim.z;
  int kstart = (int)blockIdx.z * Ksub;
  int addbias = (blockIdx.z == 0);

  int wid = tid >> 6, lane = tid & 63, quad = lane >> 4, lm = lane & 15;
  int mrow = (wid & 1) * 32, ncol = (wid >> 1) * 32;

  f32x4 acc[2][2] = {};

  int sr = tid >> 2, sc = (tid & 3) * 16;

  for (int k0 = kstart; k0 < kstart + Ksub; k0 += 64) {
    const u16* p;
    p = Ahp + (size_t)(row0 + sr) * lda + k0 + sc;
    uint4 a0 = *(const uint4*)p, a1 = *(const uint4*)(p + 8);
    p = Alp + (size_t)(row0 + sr) * lda + k0 + sc;
    uint4 a2 = *(const uint4*)p, a3 = *(const uint4*)(p + 8);
    p = Whp + (wrow0 + sr) * (size_t)ldw + k0 + sc;
    uint4 w0 = *(const uint4*)p, w1 = *(const uint4*)(p + 8);
    p = Wlp + (wrow0 + sr) * (size_t)ldw + k0 + sc;
    uint4 w2 = *(const uint4*)p, w3 = *(const uint4*)(p + 8);
    __syncthreads();
    *(uint4*)&sAh[sr][sc] = a0; *(uint4*)&sAh[sr][sc + 8] = a1;
    *(uint4*)&sAl[sr][sc] = a2; *(uint4*)&sAl[sr][sc + 8] = a3;
    *(uint4*)&sBh[sr][sc] = w0; *(uint4*)&sBh[sr][sc + 8] = w1;
    *(uint4*)&sBl[sr][sc] = w2; *(uint4*)&sBl[sr][sc + 8] = w3;
    __syncthreads();
#pragma unroll
    for (int ks = 0; ks < 2; ++ks) {
      bf16x8 ah[2], al[2], wh[2], wl[2];
#pragma unroll
      for (int mi = 0; mi < 2; ++mi) {
        ah[mi] = *(const bf16x8*)&sAh[mrow + mi * 16 + lm][ks * 32 + quad * 8];
        al[mi] = *(const bf16x8*)&sAl[mrow + mi * 16 + lm][ks * 32 + quad * 8];
      }
#pragma unroll
      for (int ni = 0; ni < 2; ++ni) {
        wh[ni] = *(const bf16x8*)&sBh[ncol + ni * 16 + lm][ks * 32 + quad * 8];
        wl[ni] = *(const bf16x8*)&sBl[ncol + ni * 16 + lm][ks * 32 + quad * 8];
      }
#pragma unroll
      for (int mi = 0; mi < 2; ++mi)
#pragma unroll
        for (int ni = 0; ni < 2; ++ni) {
          acc[mi][ni] = __builtin_amdgcn_mfma_f32_16x16x32_bf16(ah[mi], wh[ni], acc[mi][ni], 0, 0, 0);
          acc[mi][ni] = __builtin_amdgcn_mfma_f32_16x16x32_bf16(al[mi], wh[ni], acc[mi][ni], 0, 0, 0);
          acc[mi][ni] = __builtin_amdgcn_mfma_f32_16x16x32_bf16(ah[mi], wl[ni], acc[mi][ni], 0, 0, 0);
        }
    }
  }
  // C/D layout: col=lane&15, row=quad*4+reg (m89-verified)
#pragma unroll
  for (int mi = 0; mi < 2; ++mi) {
#pragma unroll
    for (int ni = 0; ni < 2; ++ni) {
      int colg = col0 + ncol + ni * 16 + lm;
      const void* bp; size_t bo;
      if (rsplit) { bp = b1; bo = bo1 + colg; }
      else {
        int seg = colg >> bshift;
        bp = (seg == 0) ? b0 : ((seg == 1) ? b1 : b2);
        bo = (seg == 0) ? bo0 : ((seg == 1) ? bo1 : bo2);
        bo += (size_t)colg - ((size_t)seg << bshift);
      }
      float bv = addbias ? ldin(bp, bo, isbf) : 0.f;
#pragma unroll
      for (int r = 0; r < 4; ++r) {
        int rowg = row0 + mrow + mi * 16 + quad * 4 + r;
        float v = acc[mi][ni][r] + bv;
        if (act) v = v * 0.5f * (1.f + erff(v * 0.70710678118654752f));
        if (mode == 3 && colg >= 1024) {
          int gg = rowg >> 7;
          size_t o = ((size_t)(gg * 512) + (colg - 1024)) * 128 + (rowg & 127);
          u16 hh = f2bf(v); Vh[o] = hh; Vl[o] = f2bf(v - bfu(hh));
        } else {
          size_t o = (size_t)rowg * ldc + colg;
          if (mode == 0) C[o] = v;
          else if (mode == 1) atomicAdd(&C[o], v);
          else { u16 hh = f2bf(v); Chp[o] = hh; Clp[o] = f2bf(v - bfu(hh)); }
        }
      }
    }
  }
}

// MFMA attention: grid 128 = (g 8, h 4, tq 4), 256 threads (4 waves).
__global__ __launch_bounds__(256) void attn_mfma(
    const u16* __restrict__ Qh, const u16* __restrict__ Ql,
    const u16* __restrict__ Vth, const u16* __restrict__ Vtl,
    u16* __restrict__ Oh, u16* __restrict__ Ol) {
  int tq = blockIdx.x & 3;
  int h = (blockIdx.x >> 2) & 3;
  int g = blockIdx.x >> 4;
  int tid = threadIdx.x;
  int w = tid >> 6, lane = tid & 63, quad = lane >> 4, lm = lane & 15;
  __shared__ float S[32][132];

  f32x4 sacc[2][2] = {};
#pragma unroll
  for (int ks = 0; ks < 4; ++ks) {
    bf16x8 qh[2], ql[2];
#pragma unroll
    for (int mi = 0; mi < 2; ++mi) {
      size_t qi = (size_t)(g * 128 + tq * 32 + mi * 16 + lm) * 1536 + h * 128 + ks * 32 + quad * 8;
      qh[mi] = *(const bf16x8*)(Qh + qi);
      ql[mi] = *(const bf16x8*)(Ql + qi);
    }
#pragma unroll
    for (int ni = 0; ni < 2; ++ni) {
      size_t kix = (size_t)(g * 128 + w * 32 + ni * 16 + lm) * 1536 + 512 + h * 128 + ks * 32 + quad * 8;
      bf16x8 kh = *(const bf16x8*)(Qh + kix);
      bf16x8 kl = *(const bf16x8*)(Ql + kix);
#pragma unroll
      for (int mi = 0; mi < 2; ++mi) {
        sacc[mi][ni] = __builtin_amdgcn_mfma_f32_16x16x32_bf16(qh[mi], kh, sacc[mi][ni], 0, 0, 0);
        sacc[mi][ni] = __builtin_amdgcn_mfma_f32_16x16x32_bf16(ql[mi], kh, sacc[mi][ni], 0, 0, 0);
        sacc[mi][ni] = __builtin_amdgcn_mfma_f32_16x16x32_bf16(qh[mi], kl, sacc[mi][ni], 0, 0, 0);
      }
    }
  }
  const float scale = 0.08838834764831845f;
#pragma unroll
  for (int mi = 0; mi < 2; ++mi)
#pragma unroll
    for (int ni = 0; ni < 2; ++ni)
#pragma unroll
      for (int r = 0; r < 4; ++r)
        S[mi * 16 + quad * 4 + r][w * 32 + ni * 16 + lm] = sacc[mi][ni][r] * scale;
  __syncthreads();

  {
    int row = tid >> 3, j = tid & 7;
    float* sp = &S[row][j * 16];
    float v[16];
    *(float4*)(v) = *(float4*)(sp);
    *(float4*)(v + 4) = *(float4*)(sp + 4);
    *(float4*)(v + 8) = *(float4*)(sp + 8);
    *(float4*)(v + 12) = *(float4*)(sp + 12);
    float mx = v[0];
#pragma unroll
    for (int i = 1; i < 16; ++i) mx = fmaxf(mx, v[i]);
    mx = fmaxf(mx, __shfl_xor(mx, 1));
    mx = fmaxf(mx, __shfl_xor(mx, 2));
    mx = fmaxf(mx, __shfl_xor(mx, 4));
    float sum = 0.f;
#pragma unroll
    for (int i = 0; i < 16; ++i) { v[i] = expf(v[i] - mx); sum += v[i]; }
    sum += __shfl_xor(sum, 1);
    sum += __shfl_xor(sum, 2);
    sum += __shfl_xor(sum, 4);
    float inv = 1.f / sum;
#pragma unroll
    for (int i = 0; i < 16; ++i) v[i] *= inv;
    *(float4*)(sp) = *(float4*)(v);
    *(float4*)(sp + 4) = *(float4*)(v + 4);
    *(float4*)(sp + 8) = *(float4*)(v + 8);
    *(float4*)(sp + 12) = *(float4*)(v + 12);
  }
  __syncthreads();

  f32x4 oacc[2][2] = {};
#pragma unroll
  for (int ks = 0; ks < 4; ++ks) {
    bf16x8 ph[2], pl[2];
#pragma unroll
    for (int mi = 0; mi < 2; ++mi) {
      float pv[8];
      const float* srow = &S[mi * 16 + lm][ks * 32 + quad * 8];
      *(float4*)(pv) = *(const float4*)srow;
      *(float4*)(pv + 4) = *(const float4*)(srow + 4);
      bf16x8 hh, ll;
#pragma unroll
      for (int i = 0; i < 8; ++i) {
        u16 hb = f2bf(pv[i]);
        hh[i] = (short)hb;
        ll[i] = (short)f2bf(pv[i] - bfu(hb));
      }
      ph[mi] = hh; pl[mi] = ll;
    }
#pragma unroll
    for (int ni = 0; ni < 2; ++ni) {
      size_t vi = (size_t)(g * 512 + h * 128 + w * 32 + ni * 16 + lm) * 128 + ks * 32 + quad * 8;
      bf16x8 vh = *(const bf16x8*)(Vth + vi);
      bf16x8 vl = *(const bf16x8*)(Vtl + vi);
#pragma unroll
      for (int mi = 0; mi < 2; ++mi) {
        oacc[mi][ni] = __builtin_amdgcn_mfma_f32_16x16x32_bf16(ph[mi], vh, oacc[mi][ni], 0, 0, 0);
        oacc[mi][ni] = __builtin_amdgcn_mfma_f32_16x16x32_bf16(pl[mi], vh, oacc[mi][ni], 0, 0, 0);
        oacc[mi][ni] = __builtin_amdgcn_mfma_f32_16x16x32_bf16(ph[mi], vl, oacc[mi][ni], 0, 0, 0);
      }
    }
  }
#pragma unroll
  for (int mi = 0; mi < 2; ++mi)
#pragma unroll
    for (int ni = 0; ni < 2; ++ni)
#pragma unroll
      for (int r = 0; r < 4; ++r) {
        int t = tq * 32 + mi * 16 + quad * 4 + r;
        int d = w * 32 + ni * 16 + lm;
        size_t o = (size_t)(g * 128 + t) * 512 + h * 128 + d;
        float val = oacc[mi][ni][r];
        u16 hb = f2bf(val);
        Oh[o] = hb;
        Ol[o] = f2bf(val - bfu(hb));
      }
}

// emb+pos LN, both encoders (1024 rows): writes fp32 x AND hi/lo planes.
__global__ __launch_bounds__(256) void emb_ln2(
    const void* __restrict__ qe, const void* __restrict__ ae, const void* __restrict__ pos,
    const void* __restrict__ w, const void* __restrict__ b,
    float* __restrict__ x, u16* __restrict__ oh, u16* __restrict__ ol,
    const int* __restrict__ dflag) {
  const int isbf = *dflag;
  const int D = 512;
  int row = blockIdx.x;
  const void* emb = (row < 512) ? qe : ae;
  int lr = row & 511, t = row & 127;
  __shared__ float sbuf[8];
  int i0 = threadIdx.x, i1 = threadIdx.x + 256;
  float v0 = ldin(emb, (size_t)lr * D + i0, isbf) + ldin(pos, (size_t)t * D + i0, isbf);
  float v1 = ldin(emb, (size_t)lr * D + i1, isbf) + ldin(pos, (size_t)t * D + i1, isbf);
  float mean = block_sum(v0 + v1, sbuf) / 512.f;
  float d0 = v0 - mean, d1 = v1 - mean;
  float var = block_sum(d0 * d0 + d1 * d1, sbuf) / 512.f;
  float inv = 1.0f / sqrtf(var + 1e-12f);
  float r0 = ldin(w, i0, isbf) * d0 * inv + ldin(b, i0, isbf);
  float r1 = ldin(w, i1, isbf) * d1 * inv + ldin(b, i1, isbf);
  size_t o0 = (size_t)row * D + i0, o1 = (size_t)row * D + i1;
  x[o0] = r0; x[o1] = r1;
  u16 h0 = f2bf(r0); oh[o0] = h0; ol[o0] = f2bf(r0 - bfu(h0));
  u16 h1 = f2bf(r1); oh[o1] = h1; ol[o1] = f2bf(r1 - bfu(h1));
}

// LN fp32 in -> optional fp32 out (in-place safe) + hi/lo planes.
__global__ __launch_bounds__(256) void ln2(
    const float* __restrict__ in, float* __restrict__ outf,
    u16* __restrict__ oh, u16* __restrict__ ol,
    const void* __restrict__ w, const void* __restrict__ b, size_t wboff,
    const int* __restrict__ dflag) {
  const int isbf = *dflag;
  const int D = 512;
  int row = blockIdx.x;
  __shared__ float sbuf[8];
  int i0 = threadIdx.x, i1 = threadIdx.x + 256;
  float v0 = in[(size_t)row * D + i0];
  float v1 = in[(size_t)row * D + i1];
  float mean = block_sum(v0 + v1, sbuf) / 512.f;
  float d0 = v0 - mean, d1 = v1 - mean;
  float var = block_sum(d0 * d0 + d1 * d1, sbuf) / 512.f;
  float inv = 1.0f / sqrtf(var + 1e-12f);
  float r0 = ldin(w, wboff + i0, isbf) * d0 * inv + ldin(b, wboff + i0, isbf);
  float r1 = ldin(w, wboff + i1, isbf) * d1 * inv + ldin(b, wboff + i1, isbf);
  size_t o0 = (size_t)row * D + i0, o1 = (size_t)row * D + i1;
  if (outf) { outf[o0] = r0; outf[o1] = r1; }
  u16 h0 = f2bf(r0); oh[o0] = h0; ol[o0] = f2bf(r0 - bfu(h0));
  u16 h1 = f2bf(r1); oh[o1] = h1; ol[o1] = f2bf(r1 - bfu(h1));
}

// proj (blocks 0..1023) + gram (blocks 1024..1048), merged.
__global__ __launch_bounds__(64) void projgram(const float* __restrict__ qkb,
                                               const void* __restrict__ ce,
                                               float* __restrict__ ck, float* __restrict__ G,
                                               const int* __restrict__ dflag) {
  const int isbf = *dflag;
  if (blockIdx.x < 1024) {
    int row = blockIdx.x;
#pragma unroll
    for (int c = 0; c < 5; ++c) {
      float acc = 0.f;
      for (int d = threadIdx.x; d < 512; d += 64)
        acc = fmaf(qkb[(size_t)row * 512 + d], ldin(ce, (size_t)c * 512 + d, isbf), acc);
      acc = wave_sum(acc);
      if (threadIdx.x == 0) ck[row * 5 + c] = acc;
    }
  } else {
    int i = blockIdx.x - 1024;
    int c = i / 5, c2 = i % 5;
    float acc = 0.f;
    for (int d = threadIdx.x; d < 512; d += 64)
      acc = fmaf(ldin(ce, (size_t)c * 512 + d, isbf), ldin(ce, (size_t)c2 * 512 + d, isbf), acc);
    acc = wave_sum(acc);
    if (threadIdx.x == 0) G[i] = acc;
  }
}

// sim scores + double softmax; accumulates Pbar[b][s] = sum_t p, pabar[b][c] = sum_t pa.
__global__ __launch_bounds__(128) void scores_acc(
    const float* __restrict__ qkb, const void* __restrict__ qa, const void* __restrict__ aq,
    const float* __restrict__ ck, const float* __restrict__ G,
    float* __restrict__ Pbar, float* __restrict__ pabar, const int* __restrict__ dflag) {
  const int isbf = *dflag;
  const int T1 = 128, T2 = 128, D = 512, NC = 5;
  int t = blockIdx.x & 127;
  int b = blockIdx.x >> 7;
  int s = threadIdx.x;
  const float* q = qkb;                       // rows 0..511
  const float* k = qkb + (size_t)512 * 512;   // rows 512..1023
  __shared__ float qs[512];
  __shared__ float Gs[25];
  __shared__ float qcs[5];
  __shared__ float sbuf[8];
  for (int i = threadIdx.x; i < D; i += 128) qs[i] = q[(size_t)(b * T1 + t) * D + i];
  if (threadIdx.x < NC * NC) Gs[threadIdx.x] = G[threadIdx.x];
  if (threadIdx.x < NC) qcs[threadIdx.x] = ck[(size_t)(b * T1 + t) * NC + threadIdx.x];
  __syncthreads();
  const float* krow = k + (size_t)(b * T2 + s) * D;
  float sc = 0.f;
#pragma unroll 4
  for (int d = 0; d < 512; d += 4) {
    float4 kv4 = *(const float4*)(krow + d);
    sc = fmaf(qs[d], kv4.x, sc);
    sc = fmaf(qs[d + 1], kv4.y, sc);
    sc = fmaf(qs[d + 2], kv4.z, sc);
    sc = fmaf(qs[d + 3], kv4.w, sc);
  }
  float qav[5], aqv[5];
#pragma unroll
  for (int c = 0; c < 5; ++c) {
    qav[c] = ldin(qa, (size_t)((b * T1 + t) * T2 + s) * NC + c, isbf);
    aqv[c] = ldin(aq, (size_t)((b * T2 + s) * T1 + t) * NC + c, isbf);
  }
#pragma unroll
  for (int c = 0; c < 5; ++c) {
    sc = fmaf(aqv[c], qcs[c], sc);
    sc = fmaf(qav[c], ck[(size_t)(512 + b * T2 + s) * NC + c], sc);
#pragma unroll
    for (int c2 = 0; c2 < 5; ++c2) sc = fmaf(qav[c] * Gs[c * 5 + c2], aqv[c2], sc);
  }
  float mx = block_max(sc, sbuf);
  float e = expf(sc - mx);
  float ssum = block_sum(e, sbuf);
  float p = e / ssum;
  float mx2 = block_max(p, sbuf);
  float e2 = expf(1000.f * (p - mx2));
  float s2 = block_sum(e2, sbuf);
  float pf = fminf(fmaxf(e2 / s2, 0.f), 1.f);
  atomicAdd(&Pbar[b * 128 + s], pf);
#pragma unroll
  for (int c = 0; c < 5; ++c) {
    float pc = block_sum(pf * aqv[c], sbuf);
    if (threadIdx.x == 0) atomicAdd(&pabar[b * 5 + c], pc);
  }
}

// mean-over-t + classifier, fused via column sums:
// xm[b,d] = (1/128)(sum_s Pbar[b,s] k[b,s,d] + sum_c pabar[b,c] CE[c,d]); out = xm@W+b.
__global__ __launch_bounds__(512) void meancls(
    const float* __restrict__ qkb, const float* __restrict__ Pbar, const float* __restrict__ pabar,
    const void* __restrict__ ce, const void* __restrict__ clsw, const void* __restrict__ clsb,
    void* __restrict__ out, const int* __restrict__ dflag) {
  const int isbf = *dflag;
  int b = blockIdx.x;
  int d = threadIdx.x;
  __shared__ float Ps[128];
  __shared__ float pas[5];
  __shared__ float xm[512];
  __shared__ float sbuf[8];
  if (d < 128) Ps[d] = Pbar[b * 128 + d];
  if (d < 5) pas[d] = pabar[b * 5 + d];
  __syncthreads();
  const float* k = qkb + (size_t)(512 + b * 128) * 512 + d;
  float acc = 0.f;
  for (int s = 0; s < 128; ++s) acc = fmaf(Ps[s], k[(size_t)s * 512], acc);
#pragma unroll
  for (int c = 0; c < 5; ++c) acc = fmaf(pas[c], ldin(ce, (size_t)c * 512 + d, isbf), acc);
  acc *= (1.f / 128.f);
  xm[d] = acc;
  __syncthreads();
  for (int j = 0; j < 3; ++j) {
    float v = block_sum(xm[d] * ldin(clsw, (size_t)d * 3 + j, isbf), sbuf);
    if (d == 0) {
      float val = v + ldin(clsb, j, isbf);
      if (isbf) ((u16*)out)[b * 3 + j] = f2bf(val);
      else ((float*)out)[b * 3 + j] = val;
    }
    __syncthreads();
  }
}

// ===========================================================================
// fallback round-6 kernels (used only if ws too small for fast path)
// ===========================================================================

__global__ __launch_bounds__(256) void gemm_mfma(
    const float* __restrict__ A, const void* __restrict__ W, size_t woff,
    const void* __restrict__ bias, size_t boff,
    float* __restrict__ C, int M, int N, int K, int act, int addto,
    const int* __restrict__ dflag) {
  const int isbf = *dflag;
  __shared__ __align__(16) u16 Ah[64][40];
  __shared__ __align__(16) u16 Al[64][40];
  __shared__ __align__(16) u16 Wh[64][40];
  __shared__ __align__(16) u16 Wl[64][40];
  int tid = threadIdx.x;
  int row0 = blockIdx.y * 64, col0 = blockIdx.x * 64;
  int wid = tid >> 6, lane = tid & 63;
  int quad = lane >> 4, lm = lane & 15;
  int mrow = (wid & 1) * 32, ncol = (wid >> 1) * 32;
  f32x4 acc[2][2] = {};
  int ar = tid >> 2, akc = (tid & 3) * 8;
  int bk = tid >> 3, bn0 = (tid & 7) * 8;
  for (int k0 = 0; k0 < K; k0 += 32) {
    const float* ap = A + (size_t)(row0 + ar) * K + k0 + akc;
    float av[8];
    *(float4*)(av) = *(const float4*)ap;
    *(float4*)(av + 4) = *(const float4*)(ap + 4);
    unsigned hp[4], lp[4];
#pragma unroll
    for (int j = 0; j < 4; ++j) {
      u16 h0 = f2bf(av[2 * j]);
      u16 h1 = f2bf(av[2 * j + 1]);
      u16 l0 = f2bf(av[2 * j] - bfu(h0));
      u16 l1 = f2bf(av[2 * j + 1] - bfu(h1));
      hp[j] = (unsigned)h0 | ((unsigned)h1 << 16);
      lp[j] = (unsigned)l0 | ((unsigned)l1 << 16);
    }
    *(uint4*)&Ah[ar][akc] = make_uint4(hp[0], hp[1], hp[2], hp[3]);
    *(uint4*)&Al[ar][akc] = make_uint4(lp[0], lp[1], lp[2], lp[3]);
    float wv[8];
    size_t welem = woff + (size_t)(k0 + bk) * N + col0 + bn0;
    if (isbf) {
      const u16* wp = (const u16*)W + welem;
      uint4 raw = *(const uint4*)wp;
      wv[0] = bfu((u16)(raw.x & 0xFFFF)); wv[1] = bfu((u16)(raw.x >> 16));
      wv[2] = bfu((u16)(raw.y & 0xFFFF)); wv[3] = bfu((u16)(raw.y >> 16));
      wv[4] = bfu((u16)(raw.z & 0xFFFF)); wv[5] = bfu((u16)(raw.z >> 16));
      wv[6] = bfu((u16)(raw.w & 0xFFFF)); wv[7] = bfu((u16)(raw.w >> 16));
    } else {
      const float* wp = (const float*)W + welem;
      *(float4*)(wv) = *(const float4*)wp;
      *(float4*)(wv + 4) = *(const float4*)(wp + 4);
    }
#pragma unroll
    for (int i = 0; i < 8; ++i) {
      u16 h = f2bf(wv[i]);
      u16 l = f2bf(wv[i] - bfu(h));
      Wh[bn0 + i][bk] = h;
      Wl[bn0 + i][bk] = l;
    }
    __syncthreads();
#pragma unroll
    for (int mi = 0; mi < 2; ++mi) {
      bf16x8 ah = *(const bf16x8*)&Ah[mrow + mi * 16 + lm][quad * 8];
      bf16x8 al = *(const bf16x8*)&Al[mrow + mi * 16 + lm][quad * 8];
#pragma unroll
      for (int ni = 0; ni < 2; ++ni) {
        bf16x8 wh = *(const bf16x8*)&Wh[ncol + ni * 16 + lm][quad * 8];
        bf16x8 wl = *(const bf16x8*)&Wl[ncol + ni * 16 + lm][quad * 8];
        acc[mi][ni] = __builtin_amdgcn_mfma_f32_16x16x32_bf16(ah, wh, acc[mi][ni], 0, 0, 0);
        acc[mi][ni] = __builtin_amdgcn_mfma_f32_16x16x32_bf16(al, wh, acc[mi][ni], 0, 0, 0);
        acc[mi][ni] = __builtin_amdgcn_mfma_f32_16x16x32_bf16(ah, wl, acc[mi][ni], 0, 0, 0);
      }
    }
    __syncthreads();
  }
#pragma unroll
  for (int mi = 0; mi < 2; ++mi) {
#pragma unroll
    for (int ni = 0; ni < 2; ++ni) {
      int colg = col0 + ncol + ni * 16 + lm;
      float bv = ldin(bias, boff + colg, isbf);
#pragma unroll
      for (int r = 0; r < 4; ++r) {
        int rowg = row0 + mrow + mi * 16 + quad * 4 + r;
        float v = acc[mi][ni][r] + bv;
        if (act) v = v * 0.5f * (1.f + erff(v * 0.70710678118654752f));
        size_t o = (size_t)rowg * N + colg;
        if (addto) C[o] += v; else C[o] = v;
      }
    }
  }
}

__global__ __launch_bounds__(256) void emb_ln_kernel(const void* __restrict__ emb,
                                                     const void* __restrict__ pos,
                                                     const void* __restrict__ w,
                                                     const void* __restrict__ b,
                                                     float* __restrict__ out, int T, int D,
                                                     const int* __restrict__ dflag) {
  const int isbf = *dflag;
  int row = blockIdx.x;
  int t = row % T;
  __shared__ float sbuf[8];
  int i0 = threadIdx.x, i1 = threadIdx.x + 256;
  float v0 = ldin(emb, (size_t)row * D + i0, isbf) + ldin(pos, (size_t)t * D + i0, isbf);
  float v1 = ldin(emb, (size_t)row * D + i1, isbf) + ldin(pos, (size_t)t * D + i1, isbf);
  float mean = block_sum(v0 + v1, sbuf) / (float)D;
  float d0 = v0 - mean, d1 = v1 - mean;
  float var = block_sum(d0 * d0 + d1 * d1, sbuf) / (float)D;
  float inv = 1.0f / sqrtf(var + 1e-12f);
  out[(size_t)row * D + i0] = ldin(w, i0, isbf) * d0 * inv + ldin(b, i0, isbf);
  out[(size_t)row * D + i1] = ldin(w, i1, isbf) * d1 * inv + ldin(b, i1, isbf);
}

__global__ __launch_bounds__(256) void ln_kernel(const float* __restrict__ in, float* __restrict__ out,
                                                 const void* __restrict__ w, const void* __restrict__ b,
                                                 size_t wboff, int D, const int* __restrict__ dflag) {
  const int isbf = *dflag;
  int row = blockIdx.x;
  __shared__ float sbuf[8];
  int i0 = threadIdx.x, i1 = threadIdx.x + 256;
  float v0 = in[(size_t)row * D + i0];
  float v1 = in[(size_t)row * D + i1];
  float mean = block_sum(v0 + v1, sbuf) / (float)D;
  float d0 = v0 - mean, d1 = v1 - mean;
  float var = block_sum(d0 * d0 + d1 * d1, sbuf) / (float)D;
  float inv = 1.0f / sqrtf(var + 1e-12f);
  out[(size_t)row * D + i0] = ldin(w, wboff + i0, isbf) * d0 * inv + ldin(b, wboff + i0, isbf);
  out[(size_t)row * D + i1] = ldin(w, wboff + i1, isbf) * d1 * inv + ldin(b, wboff + i1, isbf);
}

__global__ __launch_bounds__(128) void attn_kernel(const float* __restrict__ q, const float* __restrict__ k,
                                                   const float* __restrict__ v, float* __restrict__ o,
                                                   int B, int H, int T, int dk) {
  int t = blockIdx.x % T;
  int h = (blockIdx.x / T) % H;
  int b = blockIdx.x / (T * H);
  int D = H * dk;
  int tid = threadIdx.x;
  __shared__ float qs[128];
  __shared__ float ps[128];
  __shared__ float sbuf[8];
  qs[tid] = q[(size_t)(b * T + t) * D + h * dk + tid];
  __syncthreads();
  const float* krow = k + (size_t)(b * T + tid) * D + h * dk;
  float sc = 0.f;
#pragma unroll 8
  for (int d = 0; d < 128; ++d) sc = fmaf(qs[d], krow[d], sc);
  sc *= 0.08838834764831845f;
  float mx = block_max(sc, sbuf);
  float e = expf(sc - mx);
  float s = block_sum(e, sbuf);
  ps[tid] = e / s;
  __syncthreads();
  float acc = 0.f;
  for (int s2 = 0; s2 < 128; ++s2)
    acc = fmaf(ps[s2], v[(size_t)(b * T + s2) * D + h * dk + tid], acc);
  o[(size_t)(b * T + t) * D + h * dk + tid] = acc;
}

__global__ __launch_bounds__(64) void proj_ce_kernel(const float* __restrict__ q,
                                                     const void* __restrict__ ce,
                                                     float* __restrict__ out, int D, int NC,
                                                     const int* __restrict__ dflag) {
  const int isbf = *dflag;
  int row = blockIdx.x;
  for (int c = 0; c < NC; ++c) {
    float acc = 0.f;
    for (int d = threadIdx.x; d < D; d += 64)
      acc = fmaf(q[(size_t)row * D + d], ldin(ce, (size_t)c * D + d, isbf), acc);
    acc = wave_sum(acc);
    if (threadIdx.x == 0) out[row * NC + c] = acc;
  }
}

__global__ __launch_bounds__(64) void gram_kernel(const void* __restrict__ ce,
                                                  float* __restrict__ G, int D, int NC,
                                                  const int* __restrict__ dflag) {
  const int isbf = *dflag;
  int c = blockIdx.x / NC, c2 = blockIdx.x % NC;
  float acc = 0.f;
  for (int d = threadIdx.x; d < D; d += 64)
    acc = fmaf(ldin(ce, (size_t)c * D + d, isbf), ldin(ce, (size_t)c2 * D + d, isbf), acc);
  acc = wave_sum(acc);
  if (threadIdx.x == 0) G[blockIdx.x] = acc;
}

__global__ __launch_bounds__(128) void sim_scores_kernel(
    const float* __restrict__ q, const float* __restrict__ k, const void* __restrict__ qa,
    const void* __restrict__ aq, const float* __restrict__ qc, const float* __restrict__ kc,
    const float* __restrict__ G, float* __restrict__ p_out, float* __restrict__ pa_out,
    int B, int T1, int T2, int D, int NC, const int* __restrict__ dflag) {
  const int isbf = *dflag;
  int t = blockIdx.x % T1;
  int b = blockIdx.x / T1;
  int s = threadIdx.x;
  __shared__ float qs[512];
  __shared__ float Gs[25];
  __shared__ float qcs[5];
  __shared__ float sbuf[8];
  for (int i = threadIdx.x; i < D; i += 128) qs[i] = q[(size_t)(b * T1 + t) * D + i];
  if (threadIdx.x < NC * NC) Gs[threadIdx.x] = G[threadIdx.x];
  if (threadIdx.x < NC) qcs[threadIdx.x] = qc[(b * T1 + t) * NC + threadIdx.x];
  __syncthreads();
  const float* krow = k + (size_t)(b * T2 + s) * D;
  float sc = 0.f;
#pragma unroll 8
  for (int d = 0; d < 512; ++d) sc = fmaf(qs[d], krow[d], sc);
  float qav[5], aqv[5];
#pragma unroll
  for (int c = 0; c < 5; ++c) {
    qav[c] = ldin(qa, (size_t)((b * T1 + t) * T2 + s) * NC + c, isbf);
    aqv[c] = ldin(aq, (size_t)((b * T2 + s) * T1 + t) * NC + c, isbf);
  }
#pragma unroll
  for (int c = 0; c < 5; ++c) {
    sc = fmaf(aqv[c], qcs[c], sc);
    sc = fmaf(qav[c], kc[(b * T2 + s) * NC + c], sc);
#pragma unroll
    for (int c2 = 0; c2 < 5; ++c2) sc = fmaf(qav[c] * Gs[c * 5 + c2], aqv[c2], sc);
  }
  float mx = block_max(sc, sbuf);
  float e = expf(sc - mx);
  float ssum = block_sum(e, sbuf);
  float p = e / ssum;
  float mx2 = block_max(p, sbuf);
  float e2 = expf(1000.f * (p - mx2));
  float s2 = block_sum(e2, sbuf);
  float pf = fminf(fmaxf(e2 / s2, 0.f), 1.f);
  p_out[(size_t)(b * T1 + t) * T2 + s] = pf;
#pragma unroll
  for (int c = 0; c < 5; ++c) {
    float pc = block_sum(pf * aqv[c], sbuf);
    if (threadIdx.x == 0) pa_out[(b * T1 + t) * NC + c] = pc;
  }
}

__global__ __launch_bounds__(512) void sim_x_kernel(const float* __restrict__ p, const float* __restrict__ k,
                                                    const float* __restrict__ pa,
                                                    const void* __restrict__ ce,
                                                    float* __restrict__ x, int B, int T1, int T2, int D, int NC,
                                                    const int* __restrict__ dflag) {
  const int isbf = *dflag;
  int t = blockIdx.x % T1;
  int b = blockIdx.x / T1;
  int d = threadIdx.x;
  __shared__ float ps[128];
  __shared__ float pav[5];
  if (threadIdx.x < T2) ps[threadIdx.x] = p[(size_t)(b * T1 + t) * T2 + threadIdx.x];
  if (threadIdx.x < NC) pav[threadIdx.x] = pa[(b * T1 + t) * NC + threadIdx.x];
  __syncthreads();
  float acc = 0.f;
  for (int s = 0; s < 128; ++s) acc = fmaf(ps[s], k[(size_t)(b * T2 + s) * D + d], acc);
#pragma unroll
  for (int c = 0; c < 5; ++c) acc = fmaf(pav[c], ldin(ce, (size_t)c * D + d, isbf), acc);
  x[(size_t)(b * T1 + t) * D + d] = acc;
}

__global__ __launch_bounds__(512) void mean_kernel(const float* __restrict__ x, float* __restrict__ xm,
                                                   int T, int D) {
  int b = blockIdx.x;
  int d = threadIdx.x;
  float acc = 0.f;
  for (int t = 0; t < T; ++t) acc += x[(size_t)(b * T + t) * D + d];
  xm[(size_t)b * D + d] = acc / (float)T;
}

__global__ __launch_bounds__(64) void cls_kernel(const float* __restrict__ xm,
                                                 const void* __restrict__ w,
                                                 const void* __restrict__ bias,
                                                 void* __restrict__ out, int D, int NO,
                                                 const int* __restrict__ dflag) {
  const int isbf = *dflag;
  int j = blockIdx.x % NO;
  int b = blockIdx.x / NO;
  float acc = 0.f;
  for (int d = threadIdx.x; d < D; d += 64)
    acc = fmaf(xm[(size_t)b * D + d], ldin(w, (size_t)d * NO + j, isbf), acc);
  acc = wave_sum(acc);
  if (threadIdx.x == 0) {
    float val = acc + ldin(bias, j, isbf);
    if (isbf) ((__hip_bfloat16*)out)[b * NO + j] = __float2bfloat16(val);
    else ((float*)out)[b * NO + j] = val;
  }
}

// ===========================================================================
extern "C" void kernel_launch(void* const* d_in, const int* in_sizes, int n_in,
                              void* d_out, int out_size, void* d_ws, size_t ws_size,
                              hipStream_t stream) {
  const int B = 4, T = 128, D = 512, H = 4, NL = 4, DFF = 2048, NC = 5;
  const void *q_emb = d_in[0], *a_emb = d_in[1], *qa = d_in[2], *aqr = d_in[3],
             *ce = d_in[4], *pos = d_in[5], *pe_w = d_in[6], *pe_b = d_in[7],
             *Wq = d_in[8], *bq = d_in[9], *Wk = d_in[10], *bk = d_in[11],
             *Wv = d_in[12], *bv = d_in[13], *Wo = d_in[14], *bo = d_in[15],
             *ff1w = d_in[16], *ff1b = d_in[17], *ff2w = d_in[18], *ff2b = d_in[19],
             *lnin_w = d_in[20], *lnin_b = d_in[21], *lnout_w = d_in[22], *lnout_b = d_in[23],
             *simWq = d_in[24], *simbq = d_in[25], *simWk = d_in[26], *simbk = d_in[27],
             *clsw = d_in[28], *clsb = d_in[29];

  const size_t REQ = 79000000ull;  // harness poison-fill shows ws ~268 MB; fallback below if smaller
  if (ws_size >= REQ) {
    // -------- FAST PATH --------
    char* base = (char*)d_ws;
    float* x = (float*)(base + 0);
    u16* xch = (u16*)(base + 2097152);
    u16* xcl = (u16*)(base + 3145728);
    u16* qkvh = (u16*)(base + 4194304);
    u16* qkvl = (u16*)(base + 7340032);
    u16* ffch = (u16*)(base + 10485760);
    u16* ffcl = (u16*)(base + 14680064);
    u16* Vth = (u16*)(base + 18874368);
    u16* Vtl = (u16*)(base + 19922944);
    float* qkb = (float*)(base + 20971520);        // [1024][512] fp32 sim q|k
    float* ck = (float*)(base + 25165824);         // [1024][5]
    float* Gbuf = (float*)(base + 25186304);       // 25
    float* Pbar = (float*)(base + 25190400);       // [4][128]
    float* pabar = (float*)(base + 25192448);      // [4][5]
    int* dflag = (int*)(base + 25196544);
    u16* wh = (u16*)(base + 26214400);             // 13,107,200 elems
    u16* wl = (u16*)(base + 52428800);
    // wAll element layout per layer l (base l*3145728):
    //   +0        QKVO transposed [2048][512] (Q rows 0-511, K, V, O 1536-2047)
    //   +1048576  FF1 transposed  [2048][512]
    //   +2097152  FF2 transposed  [512][2048]
    // sim at +12582912: [1024][512] (simWq rows 0-511, simWk 512-1023)

    init_kernel<<<1, 512, 0, stream>>>(pe_w, dflag, Pbar, pabar);
    // all weight conversion upfront (4 launches)
    convT2<<<dim3(16, 16, 16), 256, 0, stream>>>(Wq, Wk, Wv, Wo, 262144, 512, 512,
                                                 wh, wl, 3145728, 262144, 3, 2, dflag);
    convT2<<<dim3(64, 16, 4), 256, 0, stream>>>(ff1w, ff1w, ff1w, ff1w, 1048576, 512, 2048,
                                                wh + 1048576, wl + 1048576, 3145728, 0, 0, 0, dflag);
    convT2<<<dim3(16, 64, 4), 256, 0, stream>>>(ff2w, ff2w, ff2w, ff2w, 1048576, 2048, 512,
                                                wh + 2097152, wl + 2097152, 3145728, 0, 0, 0, dflag);
    convT2<<<dim3(16, 16, 2), 256, 0, stream>>>(simWq, simWk, simWk, simWk, 0, 512, 512,
                                                wh + 12582912, wl + 12582912, 0, 262144, 1, 1, dflag);

    emb_ln2<<<1024, 256, 0, stream>>>(q_emb, a_emb, pos, pe_w, pe_b, x, xch, xcl, dflag);

    for (int l = 0; l < NL; ++l) {
      size_t wbase = (size_t)l * 3145728, bD = (size_t)l * D;
      gemm_hl<<<dim3(24, 16, 1), 256, 0, stream>>>(xch, xcl, 512, wh + wbase, wl + wbase, 512,
                                                   bq, bk, bv, bD, bD, bD, 9,
                                                   nullptr, qkvh, qkvl, Vth, Vtl, 1536,
                                                   512, 0, 3, 9999, 0, dflag);
      attn_mfma<<<128, 256, 0, stream>>>(qkvh, qkvl, Vth, Vtl, xch, xcl);
      gemm_hl<<<dim3(8, 16, 2), 256, 0, stream>>>(xch, xcl, 512, wh + wbase + 786432,
                                                  wl + wbase + 786432, 512,
                                                  bo, bo, bo, bD, bD, bD, 9,
                                                  x, nullptr, nullptr, nullptr, nullptr, 512,
                                                  512, 0, 1, 9999, 0, dflag);
      ln2<<<1024, 256, 0, stream>>>(x, nullptr, xch, xcl, lnin_w, lnin_b, bD, dflag);
      gemm_hl<<<dim3(32, 16, 1), 256, 0, stream>>>(xch, xcl, 512, wh + wbase + 1048576,
                                                   wl + wbase + 1048576, 512,
                                                   ff1b, ff1b, ff1b,
                                                   (size_t)l * DFF, (size_t)l * DFF, (size_t)l * DFF, 11,
                                                   nullptr, ffch, ffcl, nullptr, nullptr, 2048,
                                                   512, 1, 2, 9999, 0, dflag);
      gemm_hl<<<dim3(8, 16, 2), 256, 0, stream>>>(ffch, ffcl, 2048, wh + wbase + 2097152,
                                                  wl + wbase + 2097152, 2048,
                                                  ff2b, ff2b, ff2b, bD, bD, bD, 9,
                                                  x, nullptr, nullptr, nullptr, nullptr, 512,
                                                  2048, 0, 1, 9999, 0, dflag);
      ln2<<<1024, 256, 0, stream>>>(x, x, xch, xcl, lnout_w, lnout_b, bD, dflag);
    }

    // Sim head
    gemm_hl<<<dim3(8, 16, 1), 256, 0, stream>>>(xch, xcl, 512, wh + 12582912, wl + 12582912, 512,
                                                simbq, simbk, simbk, 0, 0, 0, 9,
                                                qkb, nullptr, nullptr, nullptr, nullptr, 512,
                                                512, 0, 0, 8, 512, dflag);
    projgram<<<1049, 64, 0, stream>>>(qkb, ce, ck, Gbuf, dflag);
    scores_acc<<<512, 128, 0, stream>>>(qkb, qa, aqr, ck, Gbuf, Pbar, pabar, dflag);
    meancls<<<4, 512, 0, stream>>>(qkb, Pbar, pabar, ce, clsw, clsb, d_out, dflag);
    return;
  }

  // -------- FALLBACK: round-6 passing path --------
  float* ws = (float*)d_ws;
  const size_t S = (size_t)512 * 512;
  float* qe = ws;
  float* ae = ws + S;
  float* hb = ws + 2 * S;
  float* rb = ws + 3 * S;
  float* qb = rb;
  float* kb = rb + S;
  float* vb = rb + 2 * S;
  float* ob = rb + 3 * S;
  float* ffb = rb;
  float* pbuf = rb + 2 * S;
  float* pabuf = pbuf + 65536;
  float* qcbuf = pabuf + 2560;
  float* kcbuf = qcbuf + 2560;
  float* Gbuf = kcbuf + 2560;
  float* xmean = Gbuf + 32;
  float* xsim = rb + 3 * S;
  int* dflag = (int*)(ws + 7 * S);

  const int M = B * T;
  dim3 gD(8, 8), gF1(32, 8), gF2(8, 8);

  flag_kernel<<<1, 64, 0, stream>>>(pe_w, dflag);
  for (int e = 0; e < 2; ++e) {
    float* x = (e == 0) ? qe : ae;
    const void* emb = (e == 0) ? q_emb : a_emb;
    emb_ln_kernel<<<M, 256, 0, stream>>>(emb, pos, pe_w, pe_b, x, T, D, dflag);
    for (int l = 0; l < NL; ++l) {
      size_t wDD = (size_t)l * D * D, bD = (size_t)l * D;
      gemm_mfma<<<gD, 256, 0, stream>>>(x, Wq, wDD, bq, bD, qb, M, D, D, 0, 0, dflag);
      gemm_mfma<<<gD, 256, 0, stream>>>(x, Wk, wDD, bk, bD, kb, M, D, D, 0, 0, dflag);
      gemm_mfma<<<gD, 256, 0, stream>>>(x, Wv, wDD, bv, bD, vb, M, D, D, 0, 0, dflag);
      attn_kernel<<<B * H * T, 128, 0, stream>>>(qb, kb, vb, ob, B, H, T, D / H);
      gemm_mfma<<<gD, 256, 0, stream>>>(ob, Wo, wDD, bo, bD, x, M, D, D, 0, 1, dflag);
      ln_kernel<<<M, 256, 0, stream>>>(x, hb, lnin_w, lnin_b, bD, D, dflag);
      gemm_mfma<<<gF1, 256, 0, stream>>>(hb, ff1w, (size_t)l * D * DFF, ff1b, (size_t)l * DFF,
                                         ffb, M, DFF, D, 1, 0, dflag);
      gemm_mfma<<<gF2, 256, 0, stream>>>(ffb, ff2w, (size_t)l * DFF * D, ff2b, bD,
                                         x, M, D, DFF, 0, 1, dflag);
      ln_kernel<<<M, 256, 0, stream>>>(x, x, lnout_w, lnout_b, bD, D, dflag);
    }
  }
  gemm_mfma<<<gD, 256, 0, stream>>>(qe, simWq, 0, simbq, 0, qb, M, D, D, 0, 0, dflag);
  gemm_mfma<<<gD, 256, 0, stream>>>(ae, simWk, 0, simbk, 0, kb, M, D, D, 0, 0, dflag);
  proj_ce_kernel<<<M, 64, 0, stream>>>(qb, ce, qcbuf, D, NC, dflag);
  proj_ce_kernel<<<M, 64, 0, stream>>>(kb, ce, kcbuf, D, NC, dflag);
  gram_kernel<<<NC * NC, 64, 0, stream>>>(ce, Gbuf, D, NC, dflag);
  sim_scores_kernel<<<B * T, 128, 0, stream>>>(qb, kb, qa, aqr, qcbuf, kcbuf, Gbuf, pbuf, pabuf,
                                               B, T, T, D, NC, dflag);
  sim_x_kernel<<<B * T, 512, 0, stream>>>(pbuf, kb, pabuf, ce, xsim, B, T, T, D, NC, dflag);
  mean_kernel<<<B, 512, 0, stream>>>(xsim, xmean, T, D);
  cls_kernel<<<B * 3, 64, 0, stream>>>(xmean, clsw, clsb, d_out, D, 3, dflag);
}